// Round 2
// baseline (4242.168 us; speedup 1.0000x reference)
//
#include <hip/hip_runtime.h>
#include <cstdint>
#include <cstddef>

namespace {
constexpr int kNL = 32, kNE = 4, kTES = 128, kHID = 256, kNA = 32, kOBSD = 128, kT = 64, kN = 256;
constexpr int kRows = kN * kNL;     // 8192
constexpr int kG3   = 3 * kTES;     // 384
constexpr int kCG3  = 3 * kHID;     // 768

// workspace layout (in floats) — total ~22.33M floats ≈ 89.3 MB
constexpr size_t oM    = 0;
constexpr size_t oGif  = oM    + (size_t)kRows * kTES;
constexpr size_t oGib  = oGif  + (size_t)kRows * kG3;
constexpr size_t oMih  = oGib  + (size_t)kRows * kG3;
constexpr size_t oZobs = oMih  + (size_t)kRows * kCG3;
constexpr size_t oWhTf = oZobs + (size_t)kT * kN * kHID;
constexpr size_t oWhTb = oWhTf + (size_t)kTES * kG3;
constexpr size_t oCWhT = oWhTb + (size_t)kTES * kG3;
constexpr size_t oCWu  = oCWhT + (size_t)kHID * kCG3;
constexpr size_t oBraw = oCWu  + (size_t)kCG3 * 4;
constexpr size_t oP    = oBraw + (size_t)kNL * kN * kNL * 2 * kNE;
constexpr size_t oPidx = oP    + (size_t)kNL * kN * 2 * kNL * kNE;
} // namespace

// ---------------- small prep kernels ----------------

__global__ __launch_bounds__(256) void embed_kernel(const int* __restrict__ lines,
                                                    const float* __restrict__ embed_W,
                                                    float* __restrict__ M) {
  int idx = blockIdx.x * 256 + threadIdx.x;      // kRows*kTES total
  int row = idx >> 7, d = idx & 127;
  M[idx] = embed_W[(size_t)lines[row] * kTES + d];
}

__global__ __launch_bounds__(256) void transpose_kernel(const float* __restrict__ in,
                                                        float* __restrict__ outp,
                                                        int R, int C) {
  int idx = blockIdx.x * 256 + threadIdx.x;
  if (idx < R * C) {
    int r = idx / C, c = idx - r * C;
    outp[(size_t)c * R + r] = in[idx];
  }
}

__global__ __launch_bounds__(256) void extract_cwihu_kernel(const float* __restrict__ cWih,
                                                            float* __restrict__ cWu) {
  int idx = blockIdx.x * 256 + threadIdx.x;      // kCG3*4
  if (idx < kCG3 * 4) {
    int g = idx >> 2, q = idx & 3;
    cWu[idx] = cWih[(size_t)g * (kTES + kNE) + kTES + q];
  }
}

__global__ __launch_bounds__(256) void pidx_kernel(const int* __restrict__ D,
                                                   int* __restrict__ pidx) {
  int n = threadIdx.x;                           // 256 threads
  int p = 0;
  for (int t = 0; t < kT; ++t) {
    pidx[t * kN + n] = p;
    p = p + D[t * kN + n] - kNL;
    p = min(max(p, 0), kNL - 1);
  }
}

// ---------------- generic f32 GEMM:  C = A(MxK) * op(B) + bias ----------------
// transB=1: B is (N,K) row-major (ldb=row stride)  -> C += A*B^T
// transB=0: B is (K,N) row-major                   -> C += A*B
// Requires M%64==0, N%64==0, K%16==0.
__global__ __launch_bounds__(256) void gemm_bias_kernel(
    const float* __restrict__ A, const float* __restrict__ B,
    const float* __restrict__ bias, float* __restrict__ C,
    int M, int N, int K, int lda, int ldb, int ldc, int transB) {
  __shared__ float As[16][65];
  __shared__ float Bs[16][65];
  int row0 = blockIdx.y * 64, col0 = blockIdx.x * 64;
  int tid = threadIdx.x;
  int tx = tid & 15, ty = tid >> 4;
  float acc[4][4];
#pragma unroll
  for (int i = 0; i < 4; i++)
#pragma unroll
    for (int j = 0; j < 4; j++) acc[i][j] = 0.f;
  for (int k0 = 0; k0 < K; k0 += 16) {
    for (int li = tid; li < 64 * 16; li += 256) {
      int m = li >> 4, kk = li & 15;
      As[kk][m] = A[(size_t)(row0 + m) * lda + k0 + kk];
    }
    if (transB) {
      for (int li = tid; li < 64 * 16; li += 256) {
        int nn = li >> 4, kk = li & 15;
        Bs[kk][nn] = B[(size_t)(col0 + nn) * ldb + k0 + kk];
      }
    } else {
      for (int li = tid; li < 16 * 64; li += 256) {
        int kk = li >> 6, nn = li & 63;
        Bs[kk][nn] = B[(size_t)(k0 + kk) * ldb + col0 + nn];
      }
    }
    __syncthreads();
#pragma unroll
    for (int kk = 0; kk < 16; ++kk) {
      float a[4], b[4];
#pragma unroll
      for (int i = 0; i < 4; i++) a[i] = As[kk][ty * 4 + i];
#pragma unroll
      for (int j = 0; j < 4; j++) b[j] = Bs[kk][tx * 4 + j];
#pragma unroll
      for (int i = 0; i < 4; i++)
#pragma unroll
        for (int j = 0; j < 4; j++) acc[i][j] += a[i] * b[j];
    }
    __syncthreads();
  }
#pragma unroll
  for (int i = 0; i < 4; i++) {
    int r = row0 + ty * 4 + i;
#pragma unroll
    for (int j = 0; j < 4; j++) {
      int c = col0 + tx * 4 + j;
      C[(size_t)r * ldc + c] = acc[i][j] + bias[c];
    }
  }
}

// ---------------- Phase A: fused bidirectional GRU + beta MLP ----------------
// 512 blocks: blocks [0,256) = forward dir, [256,512) = backward dir.
// Each block owns 32 consecutive rows (same i, consecutive n) and runs all 32
// timesteps with h resident in LDS. Per step: S = h@Whh^T (reg-tiled), gates,
// h1 = relu(h@beta_W1+b1), Bv = sigmoid(h1@beta_W2+b2) -> Braw[i][n][l][s][e].
__global__ __launch_bounds__(256) void gru_beta_kernel(
    const float* __restrict__ Gi_f, const float* __restrict__ Gi_b,
    const float* __restrict__ WhhTf, const float* __restrict__ WhhTb,
    const float* __restrict__ gbhh_f, const float* __restrict__ gbhh_b,
    const float* __restrict__ beta_W1, const float* __restrict__ beta_b1,
    const float* __restrict__ beta_W2, const float* __restrict__ beta_b2,
    float* __restrict__ Braw) {
  __shared__ float hS[32][kTES + 4];   // 32 x 132
  __shared__ float Ws[16][kG3 + 4];    // 16 x 388
  int tid = threadIdx.x;
  int dir = blockIdx.x >> 8;
  int rbase = (blockIdx.x & 255) * 32;
  int i_idx = rbase >> 8;
  int n0 = rbase & 255;
  const float* Gi  = dir ? Gi_b : Gi_f;
  const float* WhT = dir ? WhhTb : WhhTf;
  const float* bhh = dir ? gbhh_b : gbhh_f;
  for (int li = tid; li < 32 * (kTES + 4); li += 256) (&hS[0][0])[li] = 0.f;
  __syncthreads();
  int ty = tid >> 5, tx = tid & 31;

  for (int t = 0; t < kNL; ++t) {
    // ---- S = h @ Whh^T : thread owns rows ty*4..+3, cols tx*4..+3 of each gate block
    float sacc[3][4][4];
#pragma unroll
    for (int g = 0; g < 3; g++)
#pragma unroll
      for (int i = 0; i < 4; i++)
#pragma unroll
        for (int j = 0; j < 4; j++) sacc[g][i][j] = 0.f;
    for (int k0 = 0; k0 < kTES; k0 += 16) {
      for (int li = tid; li < 16 * kG3; li += 256) {
        int kk = li / kG3, g = li - kk * kG3;
        Ws[kk][g] = WhT[(size_t)(k0 + kk) * kG3 + g];
      }
      __syncthreads();
#pragma unroll
      for (int kk = 0; kk < 16; ++kk) {
        float a[4];
#pragma unroll
        for (int i = 0; i < 4; i++) a[i] = hS[ty * 4 + i][k0 + kk];
#pragma unroll
        for (int g = 0; g < 3; ++g) {
          const float4 bv = *(const float4*)&Ws[kk][g * kTES + tx * 4];
#pragma unroll
          for (int i = 0; i < 4; i++) {
            sacc[g][i][0] += a[i] * bv.x; sacc[g][i][1] += a[i] * bv.y;
            sacc[g][i][2] += a[i] * bv.z; sacc[g][i][3] += a[i] * bv.w;
          }
        }
      }
      __syncthreads();
    }
    // ---- gates (each thread owns its (r,j) elements; in-place h update is race-free)
    int l_gi  = dir ? ((i_idx + 31 - t) & 31) : ((i_idx + t) & 31);
    int l_out = dir ? (31 - t) : t;
#pragma unroll
    for (int i = 0; i < 4; i++) {
      int r = ty * 4 + i, n = n0 + r;
      const float* gi = Gi + ((size_t)n * kNL + l_gi) * kG3 + tx * 4;
      float hn4[4];
#pragma unroll
      for (int jj = 0; jj < 4; jj++) {
        int j = tx * 4 + jj;
        float grv = gi[jj]            + sacc[0][i][jj] + bhh[j];
        float gzv = gi[jj + kTES]     + sacc[1][i][jj] + bhh[j + kTES];
        float ghn =                     sacc[2][i][jj] + bhh[j + 2 * kTES];
        float gnv = gi[jj + 2 * kTES];
        float rg = 1.f / (1.f + expf(-grv));
        float zg = 1.f / (1.f + expf(-gzv));
        float ng = tanhf(gnv + rg * ghn);
        hn4[jj] = (1.f - zg) * ng + zg * hS[r][j];
      }
      *(float4*)&hS[r][tx * 4] = make_float4(hn4[0], hn4[1], hn4[2], hn4[3]);
    }
    __syncthreads();
    // ---- h1 = relu(h @ beta_W1 + b1)  (32x128, K=128)
    float bacc[4][4];
#pragma unroll
    for (int i = 0; i < 4; i++)
#pragma unroll
      for (int j = 0; j < 4; j++) bacc[i][j] = 0.f;
    for (int k0 = 0; k0 < kTES; k0 += 16) {
      for (int li = tid; li < 16 * kTES; li += 256) {
        int kk = li >> 7, j = li & 127;
        Ws[kk][j] = beta_W1[(size_t)(k0 + kk) * kTES + j];
      }
      __syncthreads();
#pragma unroll
      for (int kk = 0; kk < 16; ++kk) {
        float a[4];
#pragma unroll
        for (int i = 0; i < 4; i++) a[i] = hS[ty * 4 + i][k0 + kk];
        const float4 bv = *(const float4*)&Ws[kk][tx * 4];
#pragma unroll
        for (int i = 0; i < 4; i++) {
          bacc[i][0] += a[i] * bv.x; bacc[i][1] += a[i] * bv.y;
          bacc[i][2] += a[i] * bv.z; bacc[i][3] += a[i] * bv.w;
        }
      }
      __syncthreads();
    }
    // ---- Bv = sigmoid(h1 @ beta_W2 + b2): partials then 32-lane shfl reduce
    float pe[4][4];
#pragma unroll
    for (int i = 0; i < 4; i++)
#pragma unroll
      for (int e = 0; e < 4; e++) pe[i][e] = 0.f;
#pragma unroll
    for (int i = 0; i < 4; i++) {
#pragma unroll
      for (int jj = 0; jj < 4; jj++) {
        int j = tx * 4 + jj;
        float h1 = fmaxf(bacc[i][jj] + beta_b1[j], 0.f);
        const float4 w2 = *(const float4*)&beta_W2[j * 4];
        pe[i][0] += h1 * w2.x; pe[i][1] += h1 * w2.y;
        pe[i][2] += h1 * w2.z; pe[i][3] += h1 * w2.w;
      }
    }
#pragma unroll
    for (int m = 1; m < 32; m <<= 1) {
#pragma unroll
      for (int i = 0; i < 4; i++)
#pragma unroll
        for (int e = 0; e < 4; e++) pe[i][e] += __shfl_xor(pe[i][e], m, 64);
    }
    if (tx < 16) {
      int i = tx >> 2, e = tx & 3;
      int r = ty * 4 + i, n = n0 + r;
      float v = 1.f / (1.f + expf(-(pe[i][e] + beta_b2[e])));
      Braw[((((size_t)i_idx * kN + n) * kNL + l_out) * 2 + dir) * kNE + e] = v;
    }
    __syncthreads();
  }
}

// ---------------- masks + cumprod + reorder -> P ----------------
__global__ __launch_bounds__(256) void pcompute_kernel(const float* __restrict__ Braw,
                                                       float* __restrict__ P) {
  int tid = blockIdx.x * 256 + threadIdx.x;      // 32768 = (i*256+n)*4+e
  int e = tid & 3;
  int in_ = tid >> 2;
  const float* src = Braw + (size_t)in_ * kNL * 2 * kNE;
  float* dst = P + (size_t)in_ * 2 * kNL * kNE;
  float c = 1.f, zl_prev = 0.f;
  for (int k = 0; k < 2 * kNL; ++k) {
    int l = k >> 1, s = k & 1;
    int lb = s ? (31 - l) : l;
    float braw = src[(lb * 2 + s) * kNE + e];
    float Bk   = (k == 0) ? 0.f : braw;
    float zl   = (k == 63) ? 0.f : Bk;
    float Bfin = (k == 63) ? 1.f : Bk;
    c *= (1.f - zl_prev);
    zl_prev = zl;
    int j = s ? (31 - l) : (32 + l);
    dst[j * kNE + e] = Bfin * c;
  }
}

// ---------------- Phase B: T=64 sequential steps, 2 envs per block ----------------
__global__ __launch_bounds__(256) void phaseB_kernel(
    const float* __restrict__ Mih, const float* __restrict__ Zobs,
    const float* __restrict__ cWhhT, const float* __restrict__ cbhh,
    const float* __restrict__ cWu, const float* __restrict__ zeta2_W,
    const float* __restrict__ actor_W, const float* __restrict__ actor_b,
    const float* __restrict__ ups_W, const float* __restrict__ ups_b,
    const float* __restrict__ crit_W, const float* __restrict__ crit_b,
    const float* __restrict__ P, const int* __restrict__ pidx,
    float* __restrict__ out) {
  __shared__ float hS[2][kHID];
  __shared__ float uS[2][kNE];
  __shared__ float giS[2][kCG3];
  __shared__ float ghS[2][kCG3];
  __shared__ float zS[2][kHID];
  __shared__ float headS[2][40];
  int tid = threadIdx.x;
  int n0 = blockIdx.x * 2;
  for (int li = tid; li < 2 * kHID; li += 256) (&hS[0][0])[li] = 0.f;
  if (tid < 8) (&uS[0][0])[tid] = 0.f;
  __syncthreads();

  for (int t = 0; t < kT; ++t) {
    int pA = pidx[t * kN + n0];
    int pB = pidx[t * kN + n0 + 1];
    // gi = Mih[n][p] + u @ cWih_u^T
    for (int o = tid; o < 2 * kCG3; o += 256) {
      int e = (o >= kCG3) ? 1 : 0;
      int g = o - e * kCG3;
      int n = n0 + e, p = e ? pB : pA;
      float v = Mih[((size_t)n * kNL + p) * kCG3 + g];
      const float4 wu = *(const float4*)&cWu[g * 4];
      v += uS[e][0] * wu.x + uS[e][1] * wu.y + uS[e][2] * wu.z + uS[e][3] * wu.w;
      giS[e][g] = v;
    }
    // gh = h @ cWhh^T + cbhh (both envs per weight load, float4 streamed)
    if (tid < 192) {
      int g = tid * 4;
      float a0[4], a1[4];
#pragma unroll
      for (int x = 0; x < 4; x++) { a0[x] = cbhh[g + x]; a1[x] = a0[x]; }
      const float4* wp = (const float4*)cWhhT;
#pragma unroll 4
      for (int d = 0; d < kHID; ++d) {
        float4 wv = wp[(size_t)d * 192 + tid];
        float h0 = hS[0][d], h1 = hS[1][d];
        a0[0] += h0 * wv.x; a0[1] += h0 * wv.y; a0[2] += h0 * wv.z; a0[3] += h0 * wv.w;
        a1[0] += h1 * wv.x; a1[1] += h1 * wv.y; a1[2] += h1 * wv.z; a1[3] += h1 * wv.w;
      }
#pragma unroll
      for (int x = 0; x < 4; x++) { ghS[0][g + x] = a0[x]; ghS[1][g + x] = a1[x]; }
    }
    __syncthreads();
    // GRU-cell gates
    for (int o = tid; o < 2 * kHID; o += 256) {
      int e = (o >= kHID) ? 1 : 0;
      int j = o - e * kHID;
      float rg = 1.f / (1.f + expf(-(giS[e][j] + ghS[e][j])));
      float zg = 1.f / (1.f + expf(-(giS[e][j + kHID] + ghS[e][j + kHID])));
      float ng = tanhf(giS[e][j + 2 * kHID] + rg * ghS[e][j + 2 * kHID]);
      hS[e][j] = (1.f - zg) * ng + zg * hS[e][j];
    }
    __syncthreads();
    // z = relu(Zobs + h @ zeta2_W[128:,:])
    if (tid < 64) {
      int j = tid * 4;
      float a0[4], a1[4];
#pragma unroll
      for (int x = 0; x < 4; x++) {
        a0[x] = Zobs[((size_t)t * kN + n0) * kHID + j + x];
        a1[x] = Zobs[((size_t)t * kN + n0 + 1) * kHID + j + x];
      }
#pragma unroll 4
      for (int d = 0; d < kHID; ++d) {
        const float4 wv = *(const float4*)&zeta2_W[((size_t)(kOBSD + d)) * kHID + j];
        float h0 = hS[0][d], h1 = hS[1][d];
        a0[0] += h0 * wv.x; a0[1] += h0 * wv.y; a0[2] += h0 * wv.z; a0[3] += h0 * wv.w;
        a1[0] += h1 * wv.x; a1[1] += h1 * wv.y; a1[2] += h1 * wv.z; a1[3] += h1 * wv.w;
      }
#pragma unroll
      for (int x = 0; x < 4; x++) {
        zS[0][j + x] = fmaxf(a0[x], 0.f);
        zS[1][j + x] = fmaxf(a1[x], 0.f);
      }
    }
    __syncthreads();
    // heads: 32 actor + 4 ups + 1 crit logits per env
    {
      int e = tid >> 7, o = tid & 127;
      if (o < 37) {
        float a; const float* w; int ldw;
        if (o < kNA)            { a = actor_b[o];        w = actor_W + o;        ldw = kNA; }
        else if (o < kNA + kNE) { a = ups_b[o - kNA];    w = ups_W + (o - kNA);  ldw = kNE; }
        else                    { a = crit_b[0];         w = crit_W;             ldw = 1;   }
        for (int d = 0; d < kHID; ++d) a += zS[e][d] * w[(size_t)d * ldw];
        headS[e][o] = a;
      }
    }
    __syncthreads();
    // softmaxes
    if (tid < 2) {
      int e = tid;
      float mx = headS[e][0];
      for (int a2 = 1; a2 < kNA; a2++) mx = fmaxf(mx, headS[e][a2]);
      float sum = 0.f;
      for (int a2 = 0; a2 < kNA; a2++) { float ex = expf(headS[e][a2] - mx); headS[e][a2] = ex; sum += ex; }
      float inv = 1.f / sum;
      for (int a2 = 0; a2 < kNA; a2++) headS[e][a2] *= inv;
      float mu = headS[e][32];
      for (int q = 1; q < kNE; q++) mu = fmaxf(mu, headS[e][32 + q]);
      float su = 0.f; float ev[kNE];
      for (int q = 0; q < kNE; q++) { ev[q] = expf(headS[e][32 + q] - mu); su += ev[q]; }
      float iu = 1.f / su;
      for (int q = 0; q < kNE; q++) uS[e][q] = ev[q] * iu;
    }
    __syncthreads();
    // outputs: [a_probs(32) | d_probs(64) | v(1)]
    if (tid < 2 * 97) {
      int e = tid / 97, c = tid - e * 97;
      int n = n0 + e;
      float val;
      if (c < kNA) val = headS[e][c];
      else if (c < kNA + 2 * kNL) {
        int k = c - kNA;
        int p = e ? pB : pA;
        const float4 wv = *(const float4*)&P[(((size_t)p * kN + n) * (2 * kNL) + k) * kNE];
        val = wv.x * uS[e][0] + wv.y * uS[e][1] + wv.z * uS[e][2] + wv.w * uS[e][3];
      } else val = headS[e][36];
      out[((size_t)t * kN + n) * 97 + c] = val;
    }
    __syncthreads();
  }
}

// ---------------- launch ----------------
extern "C" void kernel_launch(void* const* d_in, const int* in_sizes, int n_in,
                              void* d_out, int out_size, void* d_ws, size_t ws_size,
                              hipStream_t stream) {
  (void)in_sizes; (void)n_in; (void)out_size; (void)ws_size;
  const int*   lines   = (const int*)d_in[0];
  const float* obs     = (const float*)d_in[1];
  const int*   D       = (const int*)d_in[2];
  const float* embed_W = (const float*)d_in[3];
  const float* gWih_f  = (const float*)d_in[4];
  const float* gWhh_f  = (const float*)d_in[5];
  const float* gbih_f  = (const float*)d_in[6];
  const float* gbhh_f  = (const float*)d_in[7];
  const float* gWih_b  = (const float*)d_in[8];
  const float* gWhh_b  = (const float*)d_in[9];
  const float* gbih_b  = (const float*)d_in[10];
  const float* gbhh_b  = (const float*)d_in[11];
  const float* beta_W1 = (const float*)d_in[12];
  const float* beta_b1 = (const float*)d_in[13];
  const float* beta_W2 = (const float*)d_in[14];
  const float* beta_b2 = (const float*)d_in[15];
  const float* cWih    = (const float*)d_in[16];
  const float* cWhh    = (const float*)d_in[17];
  const float* cbih    = (const float*)d_in[18];
  const float* cbhh    = (const float*)d_in[19];
  const float* zeta2_W = (const float*)d_in[20];
  const float* zeta2_b = (const float*)d_in[21];
  const float* actor_W = (const float*)d_in[22];
  const float* actor_b = (const float*)d_in[23];
  const float* ups_W   = (const float*)d_in[24];
  const float* ups_b   = (const float*)d_in[25];
  const float* crit_W  = (const float*)d_in[26];
  const float* crit_b  = (const float*)d_in[27];

  float* ws   = (float*)d_ws;
  float* M    = ws + oM;
  float* Gif  = ws + oGif;
  float* Gib  = ws + oGib;
  float* Mih  = ws + oMih;
  float* Zobs = ws + oZobs;
  float* WhTf = ws + oWhTf;
  float* WhTb = ws + oWhTb;
  float* cWhT = ws + oCWhT;
  float* cWu  = ws + oCWu;
  float* Braw = ws + oBraw;
  float* Pbuf = ws + oP;
  int*   pidx = (int*)(ws + oPidx);
  float* outF = (float*)d_out;

  embed_kernel<<<kRows * kTES / 256, 256, 0, stream>>>(lines, embed_W, M);
  transpose_kernel<<<(kG3 * kTES + 255) / 256, 256, 0, stream>>>(gWhh_f, WhTf, kG3, kTES);
  transpose_kernel<<<(kG3 * kTES + 255) / 256, 256, 0, stream>>>(gWhh_b, WhTb, kG3, kTES);
  transpose_kernel<<<(kCG3 * kHID + 255) / 256, 256, 0, stream>>>(cWhh, cWhT, kCG3, kHID);
  extract_cwihu_kernel<<<(kCG3 * 4 + 255) / 256, 256, 0, stream>>>(cWih, cWu);
  pidx_kernel<<<1, kN, 0, stream>>>(D, pidx);

  {
    dim3 g(kG3 / 64, kRows / 64);
    gemm_bias_kernel<<<g, 256, 0, stream>>>(M, gWih_f, gbih_f, Gif, kRows, kG3, kTES, kTES, kTES, kG3, 1);
    gemm_bias_kernel<<<g, 256, 0, stream>>>(M, gWih_b, gbih_b, Gib, kRows, kG3, kTES, kTES, kTES, kG3, 1);
  }
  {
    dim3 g(kCG3 / 64, kRows / 64);
    gemm_bias_kernel<<<g, 256, 0, stream>>>(M, cWih, cbih, Mih, kRows, kCG3, kTES, kTES, kTES + kNE, kCG3, 1);
  }
  {
    dim3 g(kHID / 64, (kT * kN) / 64);
    gemm_bias_kernel<<<g, 256, 0, stream>>>(obs, zeta2_W, zeta2_b, Zobs, kT * kN, kHID, kOBSD, kOBSD, kHID, kHID, 0);
  }

  gru_beta_kernel<<<512, 256, 0, stream>>>(Gif, Gib, WhTf, WhTb, gbhh_f, gbhh_b,
                                           beta_W1, beta_b1, beta_W2, beta_b2, Braw);
  pcompute_kernel<<<(kNL * kN * kNE) / 256, 256, 0, stream>>>(Braw, Pbuf);
  phaseB_kernel<<<kN / 2, 256, 0, stream>>>(Mih, Zobs, cWhT, cbhh, cWu, zeta2_W,
                                            actor_W, actor_b, ups_W, ups_b,
                                            crit_W, crit_b, Pbuf, pidx, outF);
}

// Round 4
// 2565.496 us; speedup vs baseline: 1.6535x; 1.6535x over previous
//
#include <hip/hip_runtime.h>
#include <cstdint>
#include <cstddef>

namespace {
constexpr int kNL = 32, kNE = 4, kTES = 128, kHID = 256, kNA = 32, kOBSD = 128, kT = 64, kN = 256;
constexpr int kRows = kN * kNL;     // 8192
constexpr int kG3   = 3 * kTES;     // 384
constexpr int kCG3  = 3 * kHID;     // 768

// workspace layout (in floats) — total ~22.36M floats ≈ 89.4 MB
constexpr size_t oM    = 0;
constexpr size_t oGif  = oM    + (size_t)kRows * kTES;
constexpr size_t oGib  = oGif  + (size_t)kRows * kG3;
constexpr size_t oMih  = oGib  + (size_t)kRows * kG3;
constexpr size_t oZobs = oMih  + (size_t)kRows * kCG3;
constexpr size_t oWhTf = oZobs + (size_t)kT * kN * kHID;   // whh_f bf16 hi+lo (2*49152 u16)
constexpr size_t oWhTb = oWhTf + (size_t)kTES * kG3;       // whh_b bf16 hi+lo
constexpr size_t oCWhT = oWhTb + (size_t)kTES * kG3;
constexpr size_t oCWu  = oCWhT + (size_t)kHID * kCG3;
constexpr size_t oBraw = oCWu  + (size_t)kCG3 * 4;
constexpr size_t oP    = oBraw + (size_t)kNL * kN * kNL * 2 * kNE;
constexpr size_t oPidx = oP    + (size_t)kNL * kN * 2 * kNL * kNE;
constexpr size_t oW1T  = oPidx + (size_t)kT * kN;          // 16384 u16 = 8192 floats
} // namespace

typedef unsigned short u16;
typedef __attribute__((ext_vector_type(8))) short short8v;
typedef __attribute__((ext_vector_type(4))) float f32x4;

__device__ __forceinline__ u16 f2bf(float x) {
  unsigned b = __float_as_uint(x);
  unsigned r = (b + 0x7FFFu + ((b >> 16) & 1u)) >> 16;
  return (u16)r;
}
__device__ __forceinline__ float bf2f(u16 u) { return __uint_as_float(((unsigned)u) << 16); }

// ---------------- small prep kernels ----------------

__global__ __launch_bounds__(256) void embed_kernel(const int* __restrict__ lines,
                                                    const float* __restrict__ embed_W,
                                                    float* __restrict__ M) {
  int idx = blockIdx.x * 256 + threadIdx.x;      // kRows*kTES total
  int row = idx >> 7, d = idx & 127;
  M[idx] = embed_W[(size_t)lines[row] * kTES + d];
}

__global__ __launch_bounds__(256) void transpose_kernel(const float* __restrict__ in,
                                                        float* __restrict__ outp,
                                                        int R, int C) {
  int idx = blockIdx.x * 256 + threadIdx.x;
  if (idx < R * C) {
    int r = idx / C, c = idx - r * C;
    outp[(size_t)c * R + r] = in[idx];
  }
}

__global__ __launch_bounds__(256) void extract_cwihu_kernel(const float* __restrict__ cWih,
                                                            float* __restrict__ cWu) {
  int idx = blockIdx.x * 256 + threadIdx.x;      // kCG3*4
  if (idx < kCG3 * 4) {
    int g = idx >> 2, q = idx & 3;
    cWu[idx] = cWih[(size_t)g * (kTES + kNE) + kTES + q];
  }
}

__global__ __launch_bounds__(256) void pidx_kernel(const int* __restrict__ D,
                                                   int* __restrict__ pidx) {
  int n = threadIdx.x;                           // 256 threads
  int p = 0;
  for (int t = 0; t < kT; ++t) {
    pidx[t * kN + n] = p;
    p = p + D[t * kN + n] - kNL;
    p = min(max(p, 0), kNL - 1);
  }
}

// split f32 -> bf16 hi + bf16 lo (hi+lo reconstructs ~17 mantissa bits)
__global__ __launch_bounds__(256) void bfsplit_kernel(const float* __restrict__ src,
                                                      u16* __restrict__ hi,
                                                      u16* __restrict__ lo, int n) {
  int i = blockIdx.x * 256 + threadIdx.x;
  if (i < n) {
    float x = src[i];
    u16 h = f2bf(x);
    hi[i] = h;
    lo[i] = f2bf(x - bf2f(h));
  }
}

// beta_W1 (k,col) f32 -> W1T (col,k) bf16-hi
__global__ __launch_bounds__(256) void w1t_kernel(const float* __restrict__ W1,
                                                  u16* __restrict__ w1t) {
  int i = blockIdx.x * 256 + threadIdx.x;        // 16384
  int k = i >> 7, c = i & 127;
  w1t[c * 128 + k] = f2bf(W1[i]);
}

// ---------------- generic f32 GEMM:  C = A(MxK) * op(B) + bias ----------------
__global__ __launch_bounds__(256) void gemm_bias_kernel(
    const float* __restrict__ A, const float* __restrict__ B,
    const float* __restrict__ bias, float* __restrict__ C,
    int M, int N, int K, int lda, int ldb, int ldc, int transB) {
  __shared__ float As[16][65];
  __shared__ float Bs[16][65];
  int row0 = blockIdx.y * 64, col0 = blockIdx.x * 64;
  int tid = threadIdx.x;
  int tx = tid & 15, ty = tid >> 4;
  float acc[4][4];
#pragma unroll
  for (int i = 0; i < 4; i++)
#pragma unroll
    for (int j = 0; j < 4; j++) acc[i][j] = 0.f;
  for (int k0 = 0; k0 < K; k0 += 16) {
    for (int li = tid; li < 64 * 16; li += 256) {
      int m = li >> 4, kk = li & 15;
      As[kk][m] = A[(size_t)(row0 + m) * lda + k0 + kk];
    }
    if (transB) {
      for (int li = tid; li < 64 * 16; li += 256) {
        int nn = li >> 4, kk = li & 15;
        Bs[kk][nn] = B[(size_t)(col0 + nn) * ldb + k0 + kk];
      }
    } else {
      for (int li = tid; li < 16 * 64; li += 256) {
        int kk = li >> 6, nn = li & 63;
        Bs[kk][nn] = B[(size_t)(k0 + kk) * ldb + col0 + nn];
      }
    }
    __syncthreads();
#pragma unroll
    for (int kk = 0; kk < 16; ++kk) {
      float a[4], b[4];
#pragma unroll
      for (int i = 0; i < 4; i++) a[i] = As[kk][ty * 4 + i];
#pragma unroll
      for (int j = 0; j < 4; j++) b[j] = Bs[kk][tx * 4 + j];
#pragma unroll
      for (int i = 0; i < 4; i++)
#pragma unroll
        for (int j = 0; j < 4; j++) acc[i][j] += a[i] * b[j];
    }
    __syncthreads();
  }
#pragma unroll
  for (int i = 0; i < 4; i++) {
    int r = row0 + ty * 4 + i;
#pragma unroll
    for (int j = 0; j < 4; j++) {
      int c = col0 + tx * 4 + j;
      C[(size_t)r * ldc + c] = acc[i][j] + bias[c];
    }
  }
}

// ---------------- Phase A: MFMA bidirectional GRU + fused beta MLP ----------------
// 512 blocks x 512 threads (8 waves). Block = (dir, i, n0..n0+31). 32 steps with h in
// LDS as bf16 hi/lo. Wave w owns S/h1 columns [16w,16w+16). Per step:
//   S = h@Whh^T via 3-term split MFMA (full f32 accuracy), gates in regs,
//   h1 = relu(h_new@W1+b1) via MFMA (bf16-hi), B = sigmoid(h1@W2+b2) via
//   shfl + cross-wave LDS reduce -> Braw.
__global__ __launch_bounds__(512, 2) void gru_beta_mfma_kernel(
    const float* __restrict__ Gi_f, const float* __restrict__ Gi_b,
    const u16* __restrict__ whhHiF, const u16* __restrict__ whhLoF,
    const u16* __restrict__ whhHiB, const u16* __restrict__ whhLoB,
    const float* __restrict__ gbhh_f, const float* __restrict__ gbhh_b,
    const u16* __restrict__ w1t, const float* __restrict__ beta_b1,
    const float* __restrict__ beta_W2, const float* __restrict__ beta_b2,
    float* __restrict__ Braw) {
  __shared__ u16 hHi[32][136];     // stride 136 keeps 16B alignment for b128 reads
  __shared__ u16 hLo[32][136];
  __shared__ float part[32][8][4];
  const int tid = threadIdx.x;
  const int dir = blockIdx.x >> 8;
  const int rbase = (blockIdx.x & 255) * 32;
  const int i_idx = rbase >> 8, n0 = rbase & 255;
  const float* __restrict__ Gi = dir ? Gi_b : Gi_f;
  const u16* __restrict__ wHiG = dir ? whhHiB : whhHiF;
  const u16* __restrict__ wLoG = dir ? whhLoB : whhLoF;
  const float* __restrict__ bhh = dir ? gbhh_b : gbhh_f;
  const int w = tid >> 6, l = tid & 63;
  const int lc = l & 15, lk = l >> 4;
  const int col = w * 16 + lc;                   // this lane's j in [0,128)

  for (int x = tid; x < 32 * 136; x += 512) { (&hHi[0][0])[x] = 0; (&hLo[0][0])[x] = 0; }

  // weights resident in VGPRs: B-frag lane mapping col=l&15, k=8*(l>>4)+j
  short8v wHi[3][4], wLo[3][4], w1f[4];
#pragma unroll
  for (int g = 0; g < 3; ++g)
#pragma unroll
    for (int kc = 0; kc < 4; ++kc) {
      size_t off = (size_t)(g * 128 + col) * 128 + kc * 32 + lk * 8;
      wHi[g][kc] = *(const short8v*)(wHiG + off);
      wLo[g][kc] = *(const short8v*)(wLoG + off);
    }
#pragma unroll
  for (int kc = 0; kc < 4; ++kc)
    w1f[kc] = *(const short8v*)(w1t + (size_t)col * 128 + kc * 32 + lk * 8);

  const float bhh_r = bhh[col], bhh_z = bhh[col + 128], bhh_n = bhh[col + 256];
  const float b1v = beta_b1[col];
  float w2v[4];
#pragma unroll
  for (int e = 0; e < 4; ++e) w2v[e] = beta_W2[col * 4 + e];
  float hprev[2][4] = {{0.f, 0.f, 0.f, 0.f}, {0.f, 0.f, 0.f, 0.f}};
  const f32x4 vzero = {0.f, 0.f, 0.f, 0.f};
  __syncthreads();

  for (int t = 0; t < kNL; ++t) {
    const int l_gi = dir ? ((i_idx + 31 - t) & 31) : ((i_idx + t) & 31);
    const int l_out = dir ? (31 - t) : t;
    // ---- S = h_prev @ Whh^T : 3-term split (hi*Whi + lo*Whi + hi*Wlo)
    f32x4 accS[2][3];
#pragma unroll
    for (int rt = 0; rt < 2; ++rt)
#pragma unroll
      for (int g = 0; g < 3; ++g) accS[rt][g] = vzero;
#pragma unroll
    for (int kc = 0; kc < 4; ++kc) {
      const int ko = kc * 32 + lk * 8;
      short8v a0 = *(const short8v*)&hHi[lc][ko];
      short8v a1 = *(const short8v*)&hHi[16 + lc][ko];
      short8v c0 = *(const short8v*)&hLo[lc][ko];
      short8v c1 = *(const short8v*)&hLo[16 + lc][ko];
#pragma unroll
      for (int g = 0; g < 3; ++g) {
        accS[0][g] = __builtin_amdgcn_mfma_f32_16x16x32_bf16(a0, wHi[g][kc], accS[0][g], 0, 0, 0);
        accS[1][g] = __builtin_amdgcn_mfma_f32_16x16x32_bf16(a1, wHi[g][kc], accS[1][g], 0, 0, 0);
        accS[0][g] = __builtin_amdgcn_mfma_f32_16x16x32_bf16(c0, wHi[g][kc], accS[0][g], 0, 0, 0);
        accS[1][g] = __builtin_amdgcn_mfma_f32_16x16x32_bf16(c1, wHi[g][kc], accS[1][g], 0, 0, 0);
        accS[0][g] = __builtin_amdgcn_mfma_f32_16x16x32_bf16(a0, wLo[g][kc], accS[0][g], 0, 0, 0);
        accS[1][g] = __builtin_amdgcn_mfma_f32_16x16x32_bf16(a1, wLo[g][kc], accS[1][g], 0, 0, 0);
      }
    }
    // ---- gates: D layout col=l&15, row=4*(l>>4)+reg matches lane ownership exactly
#pragma unroll
    for (int rt = 0; rt < 2; ++rt) {
#pragma unroll
      for (int reg = 0; reg < 4; ++reg) {
        const int row = rt * 16 + lk * 4 + reg;
        const size_t gbase = ((size_t)((n0 + row) * kNL + l_gi)) * kG3 + col;
        float gr = Gi[gbase], gz = Gi[gbase + 128], gn = Gi[gbase + 256];
        float sr = accS[rt][0][reg] + bhh_r + gr;
        float sz = accS[rt][1][reg] + bhh_z + gz;
        float sn = accS[rt][2][reg] + bhh_n;
        float rg = 1.f / (1.f + expf(-sr));
        float zg = 1.f / (1.f + expf(-sz));
        float ng = tanhf(gn + rg * sn);
        hprev[rt][reg] = (1.f - zg) * ng + zg * hprev[rt][reg];
      }
    }
    __syncthreads();   // all frag reads of h_prev done
#pragma unroll
    for (int rt = 0; rt < 2; ++rt)
#pragma unroll
      for (int reg = 0; reg < 4; ++reg) {
        const int row = rt * 16 + lk * 4 + reg;
        u16 hi = f2bf(hprev[rt][reg]);
        hHi[row][col] = hi;
        hLo[row][col] = f2bf(hprev[rt][reg] - bf2f(hi));
      }
    __syncthreads();   // new h visible
    // ---- beta MLP on h_new (G row l_out): h1 = relu(h@W1+b1)
    f32x4 accB[2] = {vzero, vzero};
#pragma unroll
    for (int kc = 0; kc < 4; ++kc) {
      const int ko = kc * 32 + lk * 8;
      short8v a0 = *(const short8v*)&hHi[lc][ko];
      short8v a1 = *(const short8v*)&hHi[16 + lc][ko];
      accB[0] = __builtin_amdgcn_mfma_f32_16x16x32_bf16(a0, w1f[kc], accB[0], 0, 0, 0);
      accB[1] = __builtin_amdgcn_mfma_f32_16x16x32_bf16(a1, w1f[kc], accB[1], 0, 0, 0);
    }
    float p[2][4][4];
#pragma unroll
    for (int rt = 0; rt < 2; ++rt)
#pragma unroll
      for (int reg = 0; reg < 4; ++reg) {
        float h1 = fmaxf(accB[rt][reg] + b1v, 0.f);
#pragma unroll
        for (int e = 0; e < 4; ++e) p[rt][reg][e] = h1 * w2v[e];
      }
#pragma unroll
    for (int m = 1; m < 16; m <<= 1)
#pragma unroll
      for (int rt = 0; rt < 2; ++rt)
#pragma unroll
        for (int reg = 0; reg < 4; ++reg)
#pragma unroll
          for (int e = 0; e < 4; ++e) p[rt][reg][e] += __shfl_xor(p[rt][reg][e], m, 64);
    if (lc == 0) {
#pragma unroll
      for (int rt = 0; rt < 2; ++rt)
#pragma unroll
        for (int reg = 0; reg < 4; ++reg)
#pragma unroll
          for (int e = 0; e < 4; ++e) part[rt * 16 + lk * 4 + reg][w][e] = p[rt][reg][e];
    }
    __syncthreads();   // partials ready
    if (tid < 128) {
      const int row = tid >> 2, e = tid & 3;
      float s = beta_b2[e];
#pragma unroll
      for (int w8 = 0; w8 < 8; ++w8) s += part[row][w8][e];
      float v = 1.f / (1.f + expf(-s));
      Braw[((((size_t)i_idx * kN + (n0 + row)) * kNL + l_out) * 2 + dir) * kNE + e] = v;
    }
  }
}

// ---------------- masks + cumprod + reorder -> P ----------------
__global__ __launch_bounds__(256) void pcompute_kernel(const float* __restrict__ Braw,
                                                       float* __restrict__ P) {
  int tid = blockIdx.x * 256 + threadIdx.x;      // 32768 = (i*256+n)*4+e
  int e = tid & 3;
  int in_ = tid >> 2;
  const float* src = Braw + (size_t)in_ * kNL * 2 * kNE;
  float* dst = P + (size_t)in_ * 2 * kNL * kNE;
  float c = 1.f, zl_prev = 0.f;
  for (int k = 0; k < 2 * kNL; ++k) {
    int l = k >> 1, s = k & 1;
    int lb = s ? (31 - l) : l;
    float braw = src[(lb * 2 + s) * kNE + e];
    float Bk   = (k == 0) ? 0.f : braw;
    float zl   = (k == 63) ? 0.f : Bk;
    float Bfin = (k == 63) ? 1.f : Bk;
    c *= (1.f - zl_prev);
    zl_prev = zl;
    int j = s ? (31 - l) : (32 + l);
    dst[j * kNE + e] = Bfin * c;
  }
}

// ---------------- Phase B: T=64 sequential steps, 2 envs per block ----------------
__global__ __launch_bounds__(256) void phaseB_kernel(
    const float* __restrict__ Mih, const float* __restrict__ Zobs,
    const float* __restrict__ cWhhT, const float* __restrict__ cbhh,
    const float* __restrict__ cWu, const float* __restrict__ zeta2_W,
    const float* __restrict__ actor_W, const float* __restrict__ actor_b,
    const float* __restrict__ ups_W, const float* __restrict__ ups_b,
    const float* __restrict__ crit_W, const float* __restrict__ crit_b,
    const float* __restrict__ P, const int* __restrict__ pidx,
    float* __restrict__ out) {
  __shared__ float hS[2][kHID];
  __shared__ float uS[2][kNE];
  __shared__ float giS[2][kCG3];
  __shared__ float ghS[2][kCG3];
  __shared__ float zS[2][kHID];
  __shared__ float headS[2][40];
  int tid = threadIdx.x;
  int n0 = blockIdx.x * 2;
  for (int li = tid; li < 2 * kHID; li += 256) (&hS[0][0])[li] = 0.f;
  if (tid < 8) (&uS[0][0])[tid] = 0.f;
  __syncthreads();

  for (int t = 0; t < kT; ++t) {
    int pA = pidx[t * kN + n0];
    int pB = pidx[t * kN + n0 + 1];
    for (int o = tid; o < 2 * kCG3; o += 256) {
      int e = (o >= kCG3) ? 1 : 0;
      int g = o - e * kCG3;
      int n = n0 + e, p = e ? pB : pA;
      float v = Mih[((size_t)n * kNL + p) * kCG3 + g];
      const float4 wu = *(const float4*)&cWu[g * 4];
      v += uS[e][0] * wu.x + uS[e][1] * wu.y + uS[e][2] * wu.z + uS[e][3] * wu.w;
      giS[e][g] = v;
    }
    if (tid < 192) {
      int g = tid * 4;
      float a0[4], a1[4];
#pragma unroll
      for (int x = 0; x < 4; x++) { a0[x] = cbhh[g + x]; a1[x] = a0[x]; }
      const float4* wp = (const float4*)cWhhT;
#pragma unroll 4
      for (int d = 0; d < kHID; ++d) {
        float4 wv = wp[(size_t)d * 192 + tid];
        float h0 = hS[0][d], h1 = hS[1][d];
        a0[0] += h0 * wv.x; a0[1] += h0 * wv.y; a0[2] += h0 * wv.z; a0[3] += h0 * wv.w;
        a1[0] += h1 * wv.x; a1[1] += h1 * wv.y; a1[2] += h1 * wv.z; a1[3] += h1 * wv.w;
      }
#pragma unroll
      for (int x = 0; x < 4; x++) { ghS[0][g + x] = a0[x]; ghS[1][g + x] = a1[x]; }
    }
    __syncthreads();
    for (int o = tid; o < 2 * kHID; o += 256) {
      int e = (o >= kHID) ? 1 : 0;
      int j = o - e * kHID;
      float rg = 1.f / (1.f + expf(-(giS[e][j] + ghS[e][j])));
      float zg = 1.f / (1.f + expf(-(giS[e][j + kHID] + ghS[e][j + kHID])));
      float ng = tanhf(giS[e][j + 2 * kHID] + rg * ghS[e][j + 2 * kHID]);
      hS[e][j] = (1.f - zg) * ng + zg * hS[e][j];
    }
    __syncthreads();
    if (tid < 64) {
      int j = tid * 4;
      float a0[4], a1[4];
#pragma unroll
      for (int x = 0; x < 4; x++) {
        a0[x] = Zobs[((size_t)t * kN + n0) * kHID + j + x];
        a1[x] = Zobs[((size_t)t * kN + n0 + 1) * kHID + j + x];
      }
#pragma unroll 4
      for (int d = 0; d < kHID; ++d) {
        const float4 wv = *(const float4*)&zeta2_W[((size_t)(kOBSD + d)) * kHID + j];
        float h0 = hS[0][d], h1 = hS[1][d];
        a0[0] += h0 * wv.x; a0[1] += h0 * wv.y; a0[2] += h0 * wv.z; a0[3] += h0 * wv.w;
        a1[0] += h1 * wv.x; a1[1] += h1 * wv.y; a1[2] += h1 * wv.z; a1[3] += h1 * wv.w;
      }
#pragma unroll
      for (int x = 0; x < 4; x++) {
        zS[0][j + x] = fmaxf(a0[x], 0.f);
        zS[1][j + x] = fmaxf(a1[x], 0.f);
      }
    }
    __syncthreads();
    {
      int e = tid >> 7, o = tid & 127;
      if (o < 37) {
        float a; const float* w; int ldw;
        if (o < kNA)            { a = actor_b[o];        w = actor_W + o;        ldw = kNA; }
        else if (o < kNA + kNE) { a = ups_b[o - kNA];    w = ups_W + (o - kNA);  ldw = kNE; }
        else                    { a = crit_b[0];         w = crit_W;             ldw = 1;   }
        for (int d = 0; d < kHID; ++d) a += zS[e][d] * w[(size_t)d * ldw];
        headS[e][o] = a;
      }
    }
    __syncthreads();
    if (tid < 2) {
      int e = tid;
      float mx = headS[e][0];
      for (int a2 = 1; a2 < kNA; a2++) mx = fmaxf(mx, headS[e][a2]);
      float sum = 0.f;
      for (int a2 = 0; a2 < kNA; a2++) { float ex = expf(headS[e][a2] - mx); headS[e][a2] = ex; sum += ex; }
      float inv = 1.f / sum;
      for (int a2 = 0; a2 < kNA; a2++) headS[e][a2] *= inv;
      float mu = headS[e][32];
      for (int q = 1; q < kNE; q++) mu = fmaxf(mu, headS[e][32 + q]);
      float su = 0.f; float ev[kNE];
      for (int q = 0; q < kNE; q++) { ev[q] = expf(headS[e][32 + q] - mu); su += ev[q]; }
      float iu = 1.f / su;
      for (int q = 0; q < kNE; q++) uS[e][q] = ev[q] * iu;
    }
    __syncthreads();
    if (tid < 2 * 97) {
      int e = tid / 97, c = tid - e * 97;
      int n = n0 + e;
      float val;
      if (c < kNA) val = headS[e][c];
      else if (c < kNA + 2 * kNL) {
        int k = c - kNA;
        int p = e ? pB : pA;
        const float4 wv = *(const float4*)&P[(((size_t)p * kN + n) * (2 * kNL) + k) * kNE];
        val = wv.x * uS[e][0] + wv.y * uS[e][1] + wv.z * uS[e][2] + wv.w * uS[e][3];
      } else val = headS[e][36];
      out[((size_t)t * kN + n) * 97 + c] = val;
    }
    __syncthreads();
  }
}

// ---------------- launch ----------------
extern "C" void kernel_launch(void* const* d_in, const int* in_sizes, int n_in,
                              void* d_out, int out_size, void* d_ws, size_t ws_size,
                              hipStream_t stream) {
  (void)in_sizes; (void)n_in; (void)out_size; (void)ws_size;
  const int*   lines   = (const int*)d_in[0];
  const float* obs     = (const float*)d_in[1];
  const int*   D       = (const int*)d_in[2];
  const float* embed_W = (const float*)d_in[3];
  const float* gWih_f  = (const float*)d_in[4];
  const float* gWhh_f  = (const float*)d_in[5];
  const float* gbih_f  = (const float*)d_in[6];
  const float* gbhh_f  = (const float*)d_in[7];
  const float* gWih_b  = (const float*)d_in[8];
  const float* gWhh_b  = (const float*)d_in[9];
  const float* gbih_b  = (const float*)d_in[10];
  const float* gbhh_b  = (const float*)d_in[11];
  const float* beta_W1 = (const float*)d_in[12];
  const float* beta_b1 = (const float*)d_in[13];
  const float* beta_W2 = (const float*)d_in[14];
  const float* beta_b2 = (const float*)d_in[15];
  const float* cWih    = (const float*)d_in[16];
  const float* cWhh    = (const float*)d_in[17];
  const float* cbih    = (const float*)d_in[18];
  const float* cbhh    = (const float*)d_in[19];
  const float* zeta2_W = (const float*)d_in[20];
  const float* zeta2_b = (const float*)d_in[21];
  const float* actor_W = (const float*)d_in[22];
  const float* actor_b = (const float*)d_in[23];
  const float* ups_W   = (const float*)d_in[24];
  const float* ups_b   = (const float*)d_in[25];
  const float* crit_W  = (const float*)d_in[26];
  const float* crit_b  = (const float*)d_in[27];

  float* ws   = (float*)d_ws;
  float* M    = ws + oM;
  float* Gif  = ws + oGif;
  float* Gib  = ws + oGib;
  float* Mih  = ws + oMih;
  float* Zobs = ws + oZobs;
  float* cWhT = ws + oCWhT;
  float* cWu  = ws + oCWu;
  float* Braw = ws + oBraw;
  float* Pbuf = ws + oP;
  int*   pidx = (int*)(ws + oPidx);
  u16*   whhHiF = (u16*)(ws + oWhTf);
  u16*   whhLoF = whhHiF + (size_t)kG3 * kTES;
  u16*   whhHiB = (u16*)(ws + oWhTb);
  u16*   whhLoB = whhHiB + (size_t)kG3 * kTES;
  u16*   w1t    = (u16*)(ws + oW1T);
  float* outF = (float*)d_out;

  embed_kernel<<<kRows * kTES / 256, 256, 0, stream>>>(lines, embed_W, M);
  bfsplit_kernel<<<(kG3 * kTES + 255) / 256, 256, 0, stream>>>(gWhh_f, whhHiF, whhLoF, kG3 * kTES);
  bfsplit_kernel<<<(kG3 * kTES + 255) / 256, 256, 0, stream>>>(gWhh_b, whhHiB, whhLoB, kG3 * kTES);
  w1t_kernel<<<(kTES * kTES + 255) / 256, 256, 0, stream>>>(beta_W1, w1t);
  transpose_kernel<<<(kCG3 * kHID + 255) / 256, 256, 0, stream>>>(cWhh, cWhT, kCG3, kHID);
  extract_cwihu_kernel<<<(kCG3 * 4 + 255) / 256, 256, 0, stream>>>(cWih, cWu);
  pidx_kernel<<<1, kN, 0, stream>>>(D, pidx);

  {
    dim3 g(kG3 / 64, kRows / 64);
    gemm_bias_kernel<<<g, 256, 0, stream>>>(M, gWih_f, gbih_f, Gif, kRows, kG3, kTES, kTES, kTES, kG3, 1);
    gemm_bias_kernel<<<g, 256, 0, stream>>>(M, gWih_b, gbih_b, Gib, kRows, kG3, kTES, kTES, kTES, kG3, 1);
  }
  {
    dim3 g(kCG3 / 64, kRows / 64);
    gemm_bias_kernel<<<g, 256, 0, stream>>>(M, cWih, cbih, Mih, kRows, kCG3, kTES, kTES, kTES + kNE, kCG3, 1);
  }
  {
    dim3 g(kHID / 64, (kT * kN) / 64);
    gemm_bias_kernel<<<g, 256, 0, stream>>>(obs, zeta2_W, zeta2_b, Zobs, kT * kN, kHID, kOBSD, kOBSD, kHID, kHID, 0);
  }

  gru_beta_mfma_kernel<<<512, 512, 0, stream>>>(Gif, Gib, whhHiF, whhLoF, whhHiB, whhLoB,
                                                gbhh_f, gbhh_b, w1t, beta_b1, beta_W2, beta_b2, Braw);
  pcompute_kernel<<<(kNL * kN * kNE) / 256, 256, 0, stream>>>(Braw, Pbuf);
  phaseB_kernel<<<kN / 2, 256, 0, stream>>>(Mih, Zobs, cWhT, cbhh, cWu, zeta2_W,
                                            actor_W, actor_b, ups_W, ups_b,
                                            crit_W, crit_b, Pbuf, pidx, outF);
}

// Round 5
// 2535.809 us; speedup vs baseline: 1.6729x; 1.0117x over previous
//
#include <hip/hip_runtime.h>
#include <cstdint>
#include <cstddef>

namespace {
constexpr int kNL = 32, kNE = 4, kTES = 128, kHID = 256, kNA = 32, kOBSD = 128, kT = 64, kN = 256;
constexpr int kRows = kN * kNL;     // 8192
constexpr int kG3   = 3 * kTES;     // 384
constexpr int kCG3  = 3 * kHID;     // 768

// workspace layout (in floats) — total ~22.36M floats ≈ 89.4 MB
constexpr size_t oM    = 0;
constexpr size_t oGif  = oM    + (size_t)kRows * kTES;
constexpr size_t oGib  = oGif  + (size_t)kRows * kG3;
constexpr size_t oMih  = oGib  + (size_t)kRows * kG3;
constexpr size_t oZobs = oMih  + (size_t)kRows * kCG3;
constexpr size_t oWhTf = oZobs + (size_t)kT * kN * kHID;   // whh_f bf16 hi+lo (2*49152 u16)
constexpr size_t oWhTb = oWhTf + (size_t)kTES * kG3;       // whh_b bf16 hi+lo
constexpr size_t oCWhT = oWhTb + (size_t)kTES * kG3;
constexpr size_t oCWu  = oCWhT + (size_t)kHID * kCG3;
constexpr size_t oBraw = oCWu  + (size_t)kCG3 * 4;
constexpr size_t oP    = oBraw + (size_t)kNL * kN * kNL * 2 * kNE;
constexpr size_t oPidx = oP    + (size_t)kNL * kN * 2 * kNL * kNE;
constexpr size_t oW1T  = oPidx + (size_t)kT * kN;          // 16384 u16 = 8192 floats
} // namespace

typedef unsigned short u16;
typedef __attribute__((ext_vector_type(8))) short short8v;
typedef __attribute__((ext_vector_type(4))) float f32x4;

__device__ __forceinline__ u16 f2bf(float x) {
  unsigned b = __float_as_uint(x);
  unsigned r = (b + 0x7FFFu + ((b >> 16) & 1u)) >> 16;
  return (u16)r;
}
__device__ __forceinline__ float bf2f(u16 u) { return __uint_as_float(((unsigned)u) << 16); }

// ---------------- small prep kernels ----------------

__global__ __launch_bounds__(256) void embed_kernel(const int* __restrict__ lines,
                                                    const float* __restrict__ embed_W,
                                                    float* __restrict__ M) {
  int idx = blockIdx.x * 256 + threadIdx.x;      // kRows*kTES total
  int row = idx >> 7, d = idx & 127;
  M[idx] = embed_W[(size_t)lines[row] * kTES + d];
}

__global__ __launch_bounds__(256) void transpose_kernel(const float* __restrict__ in,
                                                        float* __restrict__ outp,
                                                        int R, int C) {
  int idx = blockIdx.x * 256 + threadIdx.x;
  if (idx < R * C) {
    int r = idx / C, c = idx - r * C;
    outp[(size_t)c * R + r] = in[idx];
  }
}

__global__ __launch_bounds__(256) void extract_cwihu_kernel(const float* __restrict__ cWih,
                                                            float* __restrict__ cWu) {
  int idx = blockIdx.x * 256 + threadIdx.x;      // kCG3*4
  if (idx < kCG3 * 4) {
    int g = idx >> 2, q = idx & 3;
    cWu[idx] = cWih[(size_t)g * (kTES + kNE) + kTES + q];
  }
}

__global__ __launch_bounds__(256) void pidx_kernel(const int* __restrict__ D,
                                                   int* __restrict__ pidx) {
  int n = threadIdx.x;                           // 256 threads
  int p = 0;
  for (int t = 0; t < kT; ++t) {
    pidx[t * kN + n] = p;
    p = p + D[t * kN + n] - kNL;
    p = min(max(p, 0), kNL - 1);
  }
}

// split f32 -> bf16 hi + bf16 lo (hi+lo reconstructs ~17 mantissa bits)
__global__ __launch_bounds__(256) void bfsplit_kernel(const float* __restrict__ src,
                                                      u16* __restrict__ hi,
                                                      u16* __restrict__ lo, int n) {
  int i = blockIdx.x * 256 + threadIdx.x;
  if (i < n) {
    float x = src[i];
    u16 h = f2bf(x);
    hi[i] = h;
    lo[i] = f2bf(x - bf2f(h));
  }
}

// beta_W1 (k,col) f32 -> W1T (col,k) bf16-hi
__global__ __launch_bounds__(256) void w1t_kernel(const float* __restrict__ W1,
                                                  u16* __restrict__ w1t) {
  int i = blockIdx.x * 256 + threadIdx.x;        // 16384
  int k = i >> 7, c = i & 127;
  w1t[c * 128 + k] = f2bf(W1[i]);
}

// ---------------- generic f32 GEMM:  C = A(MxK) * op(B) + bias ----------------
__global__ __launch_bounds__(256) void gemm_bias_kernel(
    const float* __restrict__ A, const float* __restrict__ B,
    const float* __restrict__ bias, float* __restrict__ C,
    int M, int N, int K, int lda, int ldb, int ldc, int transB) {
  __shared__ float As[16][65];
  __shared__ float Bs[16][65];
  int row0 = blockIdx.y * 64, col0 = blockIdx.x * 64;
  int tid = threadIdx.x;
  int tx = tid & 15, ty = tid >> 4;
  float acc[4][4];
#pragma unroll
  for (int i = 0; i < 4; i++)
#pragma unroll
    for (int j = 0; j < 4; j++) acc[i][j] = 0.f;
  for (int k0 = 0; k0 < K; k0 += 16) {
    for (int li = tid; li < 64 * 16; li += 256) {
      int m = li >> 4, kk = li & 15;
      As[kk][m] = A[(size_t)(row0 + m) * lda + k0 + kk];
    }
    if (transB) {
      for (int li = tid; li < 64 * 16; li += 256) {
        int nn = li >> 4, kk = li & 15;
        Bs[kk][nn] = B[(size_t)(col0 + nn) * ldb + k0 + kk];
      }
    } else {
      for (int li = tid; li < 16 * 64; li += 256) {
        int kk = li >> 6, nn = li & 63;
        Bs[kk][nn] = B[(size_t)(k0 + kk) * ldb + col0 + nn];
      }
    }
    __syncthreads();
#pragma unroll
    for (int kk = 0; kk < 16; ++kk) {
      float a[4], b[4];
#pragma unroll
      for (int i = 0; i < 4; i++) a[i] = As[kk][ty * 4 + i];
#pragma unroll
      for (int j = 0; j < 4; j++) b[j] = Bs[kk][tx * 4 + j];
#pragma unroll
      for (int i = 0; i < 4; i++)
#pragma unroll
        for (int j = 0; j < 4; j++) acc[i][j] += a[i] * b[j];
    }
    __syncthreads();
  }
#pragma unroll
  for (int i = 0; i < 4; i++) {
    int r = row0 + ty * 4 + i;
#pragma unroll
    for (int j = 0; j < 4; j++) {
      int c = col0 + tx * 4 + j;
      C[(size_t)r * ldc + c] = acc[i][j] + bias[c];
    }
  }
}

// ---------------- Phase A: MFMA bidirectional GRU + fused beta MLP ----------------
__global__ __launch_bounds__(512, 2) void gru_beta_mfma_kernel(
    const float* __restrict__ Gi_f, const float* __restrict__ Gi_b,
    const u16* __restrict__ whhHiF, const u16* __restrict__ whhLoF,
    const u16* __restrict__ whhHiB, const u16* __restrict__ whhLoB,
    const float* __restrict__ gbhh_f, const float* __restrict__ gbhh_b,
    const u16* __restrict__ w1t, const float* __restrict__ beta_b1,
    const float* __restrict__ beta_W2, const float* __restrict__ beta_b2,
    float* __restrict__ Braw) {
  __shared__ u16 hHi[32][136];     // stride 136 keeps 16B alignment for b128 reads
  __shared__ u16 hLo[32][136];
  __shared__ float part[32][8][4];
  const int tid = threadIdx.x;
  const int dir = blockIdx.x >> 8;
  const int rbase = (blockIdx.x & 255) * 32;
  const int i_idx = rbase >> 8, n0 = rbase & 255;
  const float* __restrict__ Gi = dir ? Gi_b : Gi_f;
  const u16* __restrict__ wHiG = dir ? whhHiB : whhHiF;
  const u16* __restrict__ wLoG = dir ? whhLoB : whhLoF;
  const float* __restrict__ bhh = dir ? gbhh_b : gbhh_f;
  const int w = tid >> 6, l = tid & 63;
  const int lc = l & 15, lk = l >> 4;
  const int col = w * 16 + lc;                   // this lane's j in [0,128)

  for (int x = tid; x < 32 * 136; x += 512) { (&hHi[0][0])[x] = 0; (&hLo[0][0])[x] = 0; }

  short8v wHi[3][4], wLo[3][4], w1f[4];
#pragma unroll
  for (int g = 0; g < 3; ++g)
#pragma unroll
    for (int kc = 0; kc < 4; ++kc) {
      size_t off = (size_t)(g * 128 + col) * 128 + kc * 32 + lk * 8;
      wHi[g][kc] = *(const short8v*)(wHiG + off);
      wLo[g][kc] = *(const short8v*)(wLoG + off);
    }
#pragma unroll
  for (int kc = 0; kc < 4; ++kc)
    w1f[kc] = *(const short8v*)(w1t + (size_t)col * 128 + kc * 32 + lk * 8);

  const float bhh_r = bhh[col], bhh_z = bhh[col + 128], bhh_n = bhh[col + 256];
  const float b1v = beta_b1[col];
  float w2v[4];
#pragma unroll
  for (int e = 0; e < 4; ++e) w2v[e] = beta_W2[col * 4 + e];
  float hprev[2][4] = {{0.f, 0.f, 0.f, 0.f}, {0.f, 0.f, 0.f, 0.f}};
  const f32x4 vzero = {0.f, 0.f, 0.f, 0.f};
  __syncthreads();

  for (int t = 0; t < kNL; ++t) {
    const int l_gi = dir ? ((i_idx + 31 - t) & 31) : ((i_idx + t) & 31);
    const int l_out = dir ? (31 - t) : t;
    f32x4 accS[2][3];
#pragma unroll
    for (int rt = 0; rt < 2; ++rt)
#pragma unroll
      for (int g = 0; g < 3; ++g) accS[rt][g] = vzero;
#pragma unroll
    for (int kc = 0; kc < 4; ++kc) {
      const int ko = kc * 32 + lk * 8;
      short8v a0 = *(const short8v*)&hHi[lc][ko];
      short8v a1 = *(const short8v*)&hHi[16 + lc][ko];
      short8v c0 = *(const short8v*)&hLo[lc][ko];
      short8v c1 = *(const short8v*)&hLo[16 + lc][ko];
#pragma unroll
      for (int g = 0; g < 3; ++g) {
        accS[0][g] = __builtin_amdgcn_mfma_f32_16x16x32_bf16(a0, wHi[g][kc], accS[0][g], 0, 0, 0);
        accS[1][g] = __builtin_amdgcn_mfma_f32_16x16x32_bf16(a1, wHi[g][kc], accS[1][g], 0, 0, 0);
        accS[0][g] = __builtin_amdgcn_mfma_f32_16x16x32_bf16(c0, wHi[g][kc], accS[0][g], 0, 0, 0);
        accS[1][g] = __builtin_amdgcn_mfma_f32_16x16x32_bf16(c1, wHi[g][kc], accS[1][g], 0, 0, 0);
        accS[0][g] = __builtin_amdgcn_mfma_f32_16x16x32_bf16(a0, wLo[g][kc], accS[0][g], 0, 0, 0);
        accS[1][g] = __builtin_amdgcn_mfma_f32_16x16x32_bf16(a1, wLo[g][kc], accS[1][g], 0, 0, 0);
      }
    }
#pragma unroll
    for (int rt = 0; rt < 2; ++rt) {
#pragma unroll
      for (int reg = 0; reg < 4; ++reg) {
        const int row = rt * 16 + lk * 4 + reg;
        const size_t gbase = ((size_t)((n0 + row) * kNL + l_gi)) * kG3 + col;
        float gr = Gi[gbase], gz = Gi[gbase + 128], gn = Gi[gbase + 256];
        float sr = accS[rt][0][reg] + bhh_r + gr;
        float sz = accS[rt][1][reg] + bhh_z + gz;
        float sn = accS[rt][2][reg] + bhh_n;
        float rg = 1.f / (1.f + expf(-sr));
        float zg = 1.f / (1.f + expf(-sz));
        float ng = tanhf(gn + rg * sn);
        hprev[rt][reg] = (1.f - zg) * ng + zg * hprev[rt][reg];
      }
    }
    __syncthreads();
#pragma unroll
    for (int rt = 0; rt < 2; ++rt)
#pragma unroll
      for (int reg = 0; reg < 4; ++reg) {
        const int row = rt * 16 + lk * 4 + reg;
        u16 hi = f2bf(hprev[rt][reg]);
        hHi[row][col] = hi;
        hLo[row][col] = f2bf(hprev[rt][reg] - bf2f(hi));
      }
    __syncthreads();
    f32x4 accB[2] = {vzero, vzero};
#pragma unroll
    for (int kc = 0; kc < 4; ++kc) {
      const int ko = kc * 32 + lk * 8;
      short8v a0 = *(const short8v*)&hHi[lc][ko];
      short8v a1 = *(const short8v*)&hHi[16 + lc][ko];
      accB[0] = __builtin_amdgcn_mfma_f32_16x16x32_bf16(a0, w1f[kc], accB[0], 0, 0, 0);
      accB[1] = __builtin_amdgcn_mfma_f32_16x16x32_bf16(a1, w1f[kc], accB[1], 0, 0, 0);
    }
    float p[2][4][4];
#pragma unroll
    for (int rt = 0; rt < 2; ++rt)
#pragma unroll
      for (int reg = 0; reg < 4; ++reg) {
        float h1 = fmaxf(accB[rt][reg] + b1v, 0.f);
#pragma unroll
        for (int e = 0; e < 4; ++e) p[rt][reg][e] = h1 * w2v[e];
      }
#pragma unroll
    for (int m = 1; m < 16; m <<= 1)
#pragma unroll
      for (int rt = 0; rt < 2; ++rt)
#pragma unroll
        for (int reg = 0; reg < 4; ++reg)
#pragma unroll
          for (int e = 0; e < 4; ++e) p[rt][reg][e] += __shfl_xor(p[rt][reg][e], m, 64);
    if (lc == 0) {
#pragma unroll
      for (int rt = 0; rt < 2; ++rt)
#pragma unroll
        for (int reg = 0; reg < 4; ++reg)
#pragma unroll
          for (int e = 0; e < 4; ++e) part[rt * 16 + lk * 4 + reg][w][e] = p[rt][reg][e];
    }
    __syncthreads();
    if (tid < 128) {
      const int row = tid >> 2, e = tid & 3;
      float s = beta_b2[e];
#pragma unroll
      for (int w8 = 0; w8 < 8; ++w8) s += part[row][w8][e];
      float v = 1.f / (1.f + expf(-s));
      Braw[((((size_t)i_idx * kN + (n0 + row)) * kNL + l_out) * 2 + dir) * kNE + e] = v;
    }
  }
}

// ---------------- masks + cumprod + reorder -> P ----------------
__global__ __launch_bounds__(256) void pcompute_kernel(const float* __restrict__ Braw,
                                                       float* __restrict__ P) {
  int tid = blockIdx.x * 256 + threadIdx.x;      // 32768 = (i*256+n)*4+e
  int e = tid & 3;
  int in_ = tid >> 2;
  const float* src = Braw + (size_t)in_ * kNL * 2 * kNE;
  float* dst = P + (size_t)in_ * 2 * kNL * kNE;
  float c = 1.f, zl_prev = 0.f;
  for (int k = 0; k < 2 * kNL; ++k) {
    int l = k >> 1, s = k & 1;
    int lb = s ? (31 - l) : l;
    float braw = src[(lb * 2 + s) * kNE + e];
    float Bk   = (k == 0) ? 0.f : braw;
    float zl   = (k == 63) ? 0.f : Bk;
    float Bfin = (k == 63) ? 1.f : Bk;
    c *= (1.f - zl_prev);
    zl_prev = zl;
    int j = s ? (31 - l) : (32 + l);
    dst[j * kNE + e] = Bfin * c;
  }
}

// ---------------- Phase B v2: 128 blocks x 1024 threads, 2 envs/block ----------------
// 16 waves/CU for latency hiding; weights streamed once per step, shared by both envs.
// 5 barriers/step; output-write of step t-1 folded into phase 1 of step t.
__device__ __forceinline__ void phaseB_write_out(
    int tid, int n0, int tprev, int pPrevA, int pPrevB,
    const float (*headS)[40], const float (*uS)[8],
    const float* __restrict__ P, float* __restrict__ out) {
  if (tid < 2 * 97) {
    int e = tid / 97, c = tid - e * 97;
    int n = n0 + e;
    float val;
    if (c < kNA) val = headS[e][c];
    else if (c < kNA + 2 * kNL) {
      int k = c - kNA;
      int p = e ? pPrevB : pPrevA;
      const float4 wv = *(const float4*)&P[(((size_t)p * kN + n) * (2 * kNL) + k) * kNE];
      val = wv.x * uS[e][0] + wv.y * uS[e][1] + wv.z * uS[e][2] + wv.w * uS[e][3];
    } else val = headS[e][36];
    out[((size_t)tprev * kN + n) * 97 + c] = val;
  }
}

__global__ __launch_bounds__(1024, 4) void phaseB2_kernel(
    const float* __restrict__ Mih, const float* __restrict__ Zobs,
    const float* __restrict__ cWhhT, const float* __restrict__ cbhh,
    const float* __restrict__ cWu, const float* __restrict__ zeta2_W,
    const float* __restrict__ actor_W, const float* __restrict__ actor_b,
    const float* __restrict__ ups_W, const float* __restrict__ ups_b,
    const float* __restrict__ crit_W, const float* __restrict__ crit_b,
    const float* __restrict__ P, const int* __restrict__ pidx,
    float* __restrict__ out) {
  __shared__ float hS[2][kHID];        // 2 KB
  __shared__ float uS[2][8];
  __shared__ float giS[2][kCG3];       // 6 KB
  __shared__ float ghS[2][kCG3];       // 6 KB
  __shared__ float partZ[4][kHID][2];  // 8 KB   [ks][j][e]
  __shared__ float headP[2][37][16];   // 4.6 KB
  __shared__ float headS[2][40];
  const int tid = threadIdx.x;
  const int n0 = blockIdx.x * 2;
  for (int li = tid; li < 2 * kHID; li += 1024) (&hS[0][0])[li] = 0.f;
  if (tid < 16) (&uS[0][0])[tid] = 0.f;
  __syncthreads();

  int pPrevA = 0, pPrevB = 0;
  for (int t = 0; t < kT; ++t) {
    const int pA = pidx[t * kN + n0];
    const int pB = pidx[t * kN + n0 + 1];
    // ===== P1: outputs(t-1) + gi + gh =====
    if (tid < 256) {
      if (t > 0) phaseB_write_out(tid, n0, t - 1, pPrevA, pPrevB, headS, uS, P, out);
      // gi: 1536 outputs over 256 threads (6 each)
#pragma unroll
      for (int q6 = 0; q6 < 6; ++q6) {
        int fo = tid * 6 + q6;
        int e = fo >= kCG3 ? 1 : 0;
        int g = fo - e * kCG3;
        int p = e ? pB : pA;
        float v = Mih[((size_t)(n0 + e) * kNL + p) * kCG3 + g];
        const float4 wu = *(const float4*)&cWu[g * 4];
        v += uS[e][0] * wu.x + uS[e][1] * wu.y + uS[e][2] * wu.z + uS[e][3] * wu.w;
        giS[e][g] = v;
      }
    } else {
      // gh: 768 outputs over threads 256..1023, both envs share weight loads
      const int o = tid - 256;
      float acc0 = cbhh[o], acc1 = acc0;
#pragma unroll 8
      for (int d = 0; d < kHID; ++d) {
        float wv = cWhhT[(size_t)d * kCG3 + o];
        acc0 += hS[0][d] * wv;
        acc1 += hS[1][d] * wv;
      }
      ghS[0][o] = acc0;
      ghS[1][o] = acc1;
    }
    __syncthreads();
    // ===== P2: gates + h update =====
    if (tid < 512) {
      const int e = tid >> 8, j = tid & 255;
      float rg = 1.f / (1.f + expf(-(giS[e][j] + ghS[e][j])));
      float zg = 1.f / (1.f + expf(-(giS[e][j + kHID] + ghS[e][j + kHID])));
      float ng = tanhf(giS[e][j + 2 * kHID] + rg * ghS[e][j + 2 * kHID]);
      hS[e][j] = (1.f - zg) * ng + zg * hS[e][j];
    }
    __syncthreads();
    // ===== P3: z partials (K-split 4-way, weights shared across envs) =====
    {
      const int ks = tid >> 8, j = tid & 255;
      float acc0, acc1;
      if (ks == 0) {
        acc0 = Zobs[((size_t)t * kN + n0) * kHID + j];
        acc1 = Zobs[((size_t)t * kN + n0 + 1) * kHID + j];
      } else { acc0 = 0.f; acc1 = 0.f; }
#pragma unroll 8
      for (int dd = 0; dd < 64; ++dd) {
        int d = ks * 64 + dd;
        float wv = zeta2_W[((size_t)(kOBSD + d)) * kHID + j];
        acc0 += hS[0][d] * wv;
        acc1 += hS[1][d] * wv;
      }
      partZ[ks][j][0] = acc0;
      partZ[ks][j][1] = acc1;
    }
    __syncthreads();
    // ===== P5: head partials: 1184 units = e(2) x o(37) x ks(16), K=16 =====
    {
      for (int uid = tid; uid < 1184; uid += 1024) {
        int e = uid / 592;
        int r = uid - e * 592;
        int o = r >> 4, ks = r & 15;
        const float* wp; int ldw;
        if (o < kNA)            { wp = actor_W + o;        ldw = kNA; }
        else if (o < kNA + kNE) { wp = ups_W + (o - kNA);  ldw = kNE; }
        else                    { wp = crit_W;             ldw = 1;   }
        float acc = 0.f;
#pragma unroll
        for (int dd = 0; dd < 16; ++dd) {
          int d = ks * 16 + dd;
          float zv = partZ[0][d][e] + partZ[1][d][e] + partZ[2][d][e] + partZ[3][d][e];
          zv = fmaxf(zv, 0.f);
          acc += zv * wp[(size_t)d * ldw];
        }
        headP[e][o][ks] = acc;
      }
    }
    __syncthreads();
    // ===== P6: head reduce + softmax (waves 0,1 = envs 0,1) =====
    if (tid < 128) {
      const int e = tid >> 6, l = tid & 63;
      float v = 0.f;
      if (l < 37) {
        v = (l == 36) ? crit_b[0] : (l < kNA ? actor_b[l] : ups_b[l - kNA]);
#pragma unroll
        for (int ks = 0; ks < 16; ++ks) v += headP[e][l][ks];
      }
      // actor softmax among lanes 0..31 (masks <32 keep halves separate)
      float am = v;
#pragma unroll
      for (int m = 1; m < 32; m <<= 1) am = fmaxf(am, __shfl_xor(am, m, 64));
      float pex = expf(v - am);
      float ssum = pex;
#pragma unroll
      for (int m = 1; m < 32; m <<= 1) ssum += __shfl_xor(ssum, m, 64);
      // ups softmax among lanes 32..35 (quad butterfly)
      float um = v;
      um = fmaxf(um, __shfl_xor(um, 1, 64));
      um = fmaxf(um, __shfl_xor(um, 2, 64));
      float uex = expf(v - um);
      float usum = uex;
      usum += __shfl_xor(usum, 1, 64);
      usum += __shfl_xor(usum, 2, 64);
      if (l < 32) headS[e][l] = pex / ssum;
      else if (l < 36) uS[e][l - 32] = uex / usum;
      else if (l == 36) headS[e][36] = v;
    }
    pPrevA = pA; pPrevB = pB;
    __syncthreads();
  }
  // final outputs for t = 63
  phaseB_write_out(tid, n0, kT - 1, pPrevA, pPrevB, headS, uS, P, out);
}

// ---------------- launch ----------------
extern "C" void kernel_launch(void* const* d_in, const int* in_sizes, int n_in,
                              void* d_out, int out_size, void* d_ws, size_t ws_size,
                              hipStream_t stream) {
  (void)in_sizes; (void)n_in; (void)out_size; (void)ws_size;
  const int*   lines   = (const int*)d_in[0];
  const float* obs     = (const float*)d_in[1];
  const int*   D       = (const int*)d_in[2];
  const float* embed_W = (const float*)d_in[3];
  const float* gWih_f  = (const float*)d_in[4];
  const float* gWhh_f  = (const float*)d_in[5];
  const float* gbih_f  = (const float*)d_in[6];
  const float* gbhh_f  = (const float*)d_in[7];
  const float* gWih_b  = (const float*)d_in[8];
  const float* gWhh_b  = (const float*)d_in[9];
  const float* gbih_b  = (const float*)d_in[10];
  const float* gbhh_b  = (const float*)d_in[11];
  const float* beta_W1 = (const float*)d_in[12];
  const float* beta_b1 = (const float*)d_in[13];
  const float* beta_W2 = (const float*)d_in[14];
  const float* beta_b2 = (const float*)d_in[15];
  const float* cWih    = (const float*)d_in[16];
  const float* cWhh    = (const float*)d_in[17];
  const float* cbih    = (const float*)d_in[18];
  const float* cbhh    = (const float*)d_in[19];
  const float* zeta2_W = (const float*)d_in[20];
  const float* zeta2_b = (const float*)d_in[21];
  const float* actor_W = (const float*)d_in[22];
  const float* actor_b = (const float*)d_in[23];
  const float* ups_W   = (const float*)d_in[24];
  const float* ups_b   = (const float*)d_in[25];
  const float* crit_W  = (const float*)d_in[26];
  const float* crit_b  = (const float*)d_in[27];

  float* ws   = (float*)d_ws;
  float* M    = ws + oM;
  float* Gif  = ws + oGif;
  float* Gib  = ws + oGib;
  float* Mih  = ws + oMih;
  float* Zobs = ws + oZobs;
  float* cWhT = ws + oCWhT;
  float* cWu  = ws + oCWu;
  float* Braw = ws + oBraw;
  float* Pbuf = ws + oP;
  int*   pidx = (int*)(ws + oPidx);
  u16*   whhHiF = (u16*)(ws + oWhTf);
  u16*   whhLoF = whhHiF + (size_t)kG3 * kTES;
  u16*   whhHiB = (u16*)(ws + oWhTb);
  u16*   whhLoB = whhHiB + (size_t)kG3 * kTES;
  u16*   w1t    = (u16*)(ws + oW1T);
  float* outF = (float*)d_out;

  embed_kernel<<<kRows * kTES / 256, 256, 0, stream>>>(lines, embed_W, M);
  bfsplit_kernel<<<(kG3 * kTES + 255) / 256, 256, 0, stream>>>(gWhh_f, whhHiF, whhLoF, kG3 * kTES);
  bfsplit_kernel<<<(kG3 * kTES + 255) / 256, 256, 0, stream>>>(gWhh_b, whhHiB, whhLoB, kG3 * kTES);
  w1t_kernel<<<(kTES * kTES + 255) / 256, 256, 0, stream>>>(beta_W1, w1t);
  transpose_kernel<<<(kCG3 * kHID + 255) / 256, 256, 0, stream>>>(cWhh, cWhT, kCG3, kHID);
  extract_cwihu_kernel<<<(kCG3 * 4 + 255) / 256, 256, 0, stream>>>(cWih, cWu);
  pidx_kernel<<<1, kN, 0, stream>>>(D, pidx);

  {
    dim3 g(kG3 / 64, kRows / 64);
    gemm_bias_kernel<<<g, 256, 0, stream>>>(M, gWih_f, gbih_f, Gif, kRows, kG3, kTES, kTES, kTES, kG3, 1);
    gemm_bias_kernel<<<g, 256, 0, stream>>>(M, gWih_b, gbih_b, Gib, kRows, kG3, kTES, kTES, kTES, kG3, 1);
  }
  {
    dim3 g(kCG3 / 64, kRows / 64);
    gemm_bias_kernel<<<g, 256, 0, stream>>>(M, cWih, cbih, Mih, kRows, kCG3, kTES, kTES, kTES + kNE, kCG3, 1);
  }
  {
    dim3 g(kHID / 64, (kT * kN) / 64);
    gemm_bias_kernel<<<g, 256, 0, stream>>>(obs, zeta2_W, zeta2_b, Zobs, kT * kN, kHID, kOBSD, kOBSD, kHID, kHID, 0);
  }

  gru_beta_mfma_kernel<<<512, 512, 0, stream>>>(Gif, Gib, whhHiF, whhLoF, whhHiB, whhLoB,
                                                gbhh_f, gbhh_b, w1t, beta_b1, beta_W2, beta_b2, Braw);
  pcompute_kernel<<<(kNL * kN * kNE) / 256, 256, 0, stream>>>(Braw, Pbuf);
  phaseB2_kernel<<<kN / 2, 1024, 0, stream>>>(Mih, Zobs, cWhT, cbhh, cWu, zeta2_W,
                                              actor_W, actor_b, ups_W, ups_b,
                                              crit_W, crit_b, Pbuf, pidx, outF);
}

// Round 8
// 1706.874 us; speedup vs baseline: 2.4853x; 1.4856x over previous
//
#include <hip/hip_runtime.h>
#include <cstdint>
#include <cstddef>

namespace {
constexpr int kNL = 32, kNE = 4, kTES = 128, kHID = 256, kNA = 32, kOBSD = 128, kT = 64, kN = 256;
constexpr int kRows = kN * kNL;     // 8192
constexpr int kG3   = 3 * kTES;     // 384
constexpr int kCG3  = 3 * kHID;     // 768

// workspace layout (in floats)
constexpr size_t oM    = 0;
constexpr size_t oGif  = oM    + (size_t)kRows * kTES;
constexpr size_t oGib  = oGif  + (size_t)kRows * kG3;
constexpr size_t oMih  = oGib  + (size_t)kRows * kG3;
constexpr size_t oZobs = oMih  + (size_t)kRows * kCG3;
constexpr size_t oWhTf = oZobs + (size_t)kT * kN * kHID;   // gru whh_f bf16 hi+lo (49152 fl)
constexpr size_t oWhTb = oWhTf + (size_t)kTES * kG3;       // gru whh_b bf16 hi+lo
constexpr size_t oFrag = oWhTb + (size_t)kTES * kG3;       // phase-B frags: 149504 fl used of 199680
constexpr size_t oBraw = oFrag + (size_t)kHID * kCG3 + (size_t)kCG3 * 4;
constexpr size_t oP    = oBraw + (size_t)kNL * kN * kNL * 2 * kNE;
constexpr size_t oPidx = oP    + (size_t)kNL * kN * 2 * kNL * kNE;
constexpr size_t oW1T  = oPidx + (size_t)kT * kN;
// frag sub-offsets (u16 elements from oFrag): fWhhHi 196608 | fZeta 65536 | fHead 12288 | fCwu 24576
} // namespace

typedef unsigned short u16;
typedef __attribute__((ext_vector_type(8))) short short8v;
typedef __attribute__((ext_vector_type(4))) float f32x4;

__device__ __forceinline__ u16 f2bf(float x) {
  unsigned b = __float_as_uint(x);
  unsigned r = (b + 0x7FFFu + ((b >> 16) & 1u)) >> 16;
  return (u16)r;
}
__device__ __forceinline__ float bf2f(u16 u) { return __uint_as_float(((unsigned)u) << 16); }

// ---------------- small prep kernels ----------------

__global__ __launch_bounds__(256) void embed_kernel(const int* __restrict__ lines,
                                                    const float* __restrict__ embed_W,
                                                    float* __restrict__ M) {
  int idx = blockIdx.x * 256 + threadIdx.x;
  int row = idx >> 7, d = idx & 127;
  M[idx] = embed_W[(size_t)lines[row] * kTES + d];
}

__global__ __launch_bounds__(256) void pidx_kernel(const int* __restrict__ D,
                                                   int* __restrict__ pidx) {
  int n = threadIdx.x;
  int p = 0;
  for (int t = 0; t < kT; ++t) {
    pidx[t * kN + n] = p;
    p = p + D[t * kN + n] - kNL;
    p = min(max(p, 0), kNL - 1);
  }
}

__global__ __launch_bounds__(256) void bfsplit_kernel(const float* __restrict__ src,
                                                      u16* __restrict__ hi,
                                                      u16* __restrict__ lo, int n) {
  int i = blockIdx.x * 256 + threadIdx.x;
  if (i < n) {
    float x = src[i];
    u16 h = f2bf(x);
    hi[i] = h;
    lo[i] = f2bf(x - bf2f(h));
  }
}

__global__ __launch_bounds__(256) void w1t_kernel(const float* __restrict__ W1,
                                                  u16* __restrict__ w1t) {
  int i = blockIdx.x * 256 + threadIdx.x;
  int k = i >> 7, c = i & 127;
  w1t[c * 128 + k] = f2bf(W1[i]);
}

// ---- phase-B weight fragment packers (B-frag: col=lane&15, k=8*(lane>>4)+j) ----
__global__ __launch_bounds__(256) void packWhh_kernel(const float* __restrict__ cWhh,
                                                      u16* __restrict__ hi) {
  int idx = blockIdx.x * 256 + threadIdx.x;     // 384*512 = 196608
  int f = idx >> 9, lane = (idx >> 3) & 63, j = idx & 7;
  int g = f >> 7, rem = f & 127;
  int tile = rem >> 3, kt = rem & 7;
  int col = g * 256 + tile * 16 + (lane & 15);
  int k = kt * 32 + 8 * (lane >> 4) + j;
  hi[idx] = f2bf(cWhh[(size_t)col * kHID + k]);
}
__global__ __launch_bounds__(256) void packZeta_kernel(const float* __restrict__ zeta2_W,
                                                       u16* __restrict__ hi) {
  int idx = blockIdx.x * 256 + threadIdx.x;     // 128*512 = 65536
  int f = idx >> 9, lane = (idx >> 3) & 63, j = idx & 7;
  int tile = f >> 3, kt = f & 7;
  int col = tile * 16 + (lane & 15);
  int k = kt * 32 + 8 * (lane >> 4) + j;
  hi[idx] = f2bf(zeta2_W[(size_t)(kOBSD + k) * kHID + col]);
}
__global__ __launch_bounds__(256) void packHead_kernel(const float* __restrict__ actor_W,
                                                       const float* __restrict__ ups_W,
                                                       const float* __restrict__ crit_W,
                                                       u16* __restrict__ hi) {
  int idx = blockIdx.x * 256 + threadIdx.x;     // 24*512 = 12288
  int f = idx >> 9, lane = (idx >> 3) & 63, j = idx & 7;
  int tile = f >> 3, kt = f & 7;
  int col = tile * 16 + (lane & 15);
  int k = kt * 32 + 8 * (lane >> 4) + j;
  float x = (col < 32) ? actor_W[(size_t)k * kNA + col]
          : (col < 36) ? ups_W[(size_t)k * kNE + (col - 32)]
          : (col == 36) ? crit_W[k] : 0.f;
  hi[idx] = f2bf(x);
}
__global__ __launch_bounds__(256) void packCwu_kernel(const float* __restrict__ cWih,
                                                      u16* __restrict__ hi) {
  int idx = blockIdx.x * 256 + threadIdx.x;     // 48*512 = 24576
  int f = idx >> 9, lane = (idx >> 3) & 63, j = idx & 7;
  int g = f >> 4, tile = f & 15;
  int col = g * 256 + tile * 16 + (lane & 15);
  int k = 8 * (lane >> 4) + j;
  hi[idx] = (k < 4) ? f2bf(cWih[(size_t)col * (kTES + kNE) + kTES + k]) : (u16)0;
}

// ---------------- generic f32 GEMM:  C = A(MxK) * op(B) + bias ----------------
__global__ __launch_bounds__(256) void gemm_bias_kernel(
    const float* __restrict__ A, const float* __restrict__ B,
    const float* __restrict__ bias, float* __restrict__ C,
    int M, int N, int K, int lda, int ldb, int ldc, int transB) {
  __shared__ float As[16][65];
  __shared__ float Bs[16][65];
  int row0 = blockIdx.y * 64, col0 = blockIdx.x * 64;
  int tid = threadIdx.x;
  int tx = tid & 15, ty = tid >> 4;
  float acc[4][4];
#pragma unroll
  for (int i = 0; i < 4; i++)
#pragma unroll
    for (int j = 0; j < 4; j++) acc[i][j] = 0.f;
  for (int k0 = 0; k0 < K; k0 += 16) {
    for (int li = tid; li < 64 * 16; li += 256) {
      int m = li >> 4, kk = li & 15;
      As[kk][m] = A[(size_t)(row0 + m) * lda + k0 + kk];
    }
    if (transB) {
      for (int li = tid; li < 64 * 16; li += 256) {
        int nn = li >> 4, kk = li & 15;
        Bs[kk][nn] = B[(size_t)(col0 + nn) * ldb + k0 + kk];
      }
    } else {
      for (int li = tid; li < 16 * 64; li += 256) {
        int kk = li >> 6, nn = li & 63;
        Bs[kk][nn] = B[(size_t)(k0 + kk) * ldb + col0 + nn];
      }
    }
    __syncthreads();
#pragma unroll
    for (int kk = 0; kk < 16; ++kk) {
      float a[4], b[4];
#pragma unroll
      for (int i = 0; i < 4; i++) a[i] = As[kk][ty * 4 + i];
#pragma unroll
      for (int j = 0; j < 4; j++) b[j] = Bs[kk][tx * 4 + j];
#pragma unroll
      for (int i = 0; i < 4; i++)
#pragma unroll
        for (int j = 0; j < 4; j++) acc[i][j] += a[i] * b[j];
    }
    __syncthreads();
  }
#pragma unroll
  for (int i = 0; i < 4; i++) {
    int r = row0 + ty * 4 + i;
#pragma unroll
    for (int j = 0; j < 4; j++) {
      int c = col0 + tx * 4 + j;
      C[(size_t)r * ldc + c] = acc[i][j] + bias[c];
    }
  }
}

// ---------------- Phase A: MFMA bidirectional GRU + fused beta MLP ----------------
__global__ __launch_bounds__(512, 2) void gru_beta_mfma_kernel(
    const float* __restrict__ Gi_f, const float* __restrict__ Gi_b,
    const u16* __restrict__ whhHiF, const u16* __restrict__ whhLoF,
    const u16* __restrict__ whhHiB, const u16* __restrict__ whhLoB,
    const float* __restrict__ gbhh_f, const float* __restrict__ gbhh_b,
    const u16* __restrict__ w1t, const float* __restrict__ beta_b1,
    const float* __restrict__ beta_W2, const float* __restrict__ beta_b2,
    float* __restrict__ Braw) {
  __shared__ u16 hHi[32][136];
  __shared__ u16 hLo[32][136];
  __shared__ float part[32][8][4];
  const int tid = threadIdx.x;
  const int dir = blockIdx.x >> 8;
  const int rbase = (blockIdx.x & 255) * 32;
  const int i_idx = rbase >> 8, n0 = rbase & 255;
  const float* __restrict__ Gi = dir ? Gi_b : Gi_f;
  const u16* __restrict__ wHiG = dir ? whhHiB : whhHiF;
  const u16* __restrict__ wLoG = dir ? whhLoB : whhLoF;
  const float* __restrict__ bhh = dir ? gbhh_b : gbhh_f;
  const int w = tid >> 6, l = tid & 63;
  const int lc = l & 15, lk = l >> 4;
  const int col = w * 16 + lc;

  for (int x = tid; x < 32 * 136; x += 512) { (&hHi[0][0])[x] = 0; (&hLo[0][0])[x] = 0; }

  short8v wHi[3][4], wLo[3][4], w1f[4];
#pragma unroll
  for (int g = 0; g < 3; ++g)
#pragma unroll
    for (int kc = 0; kc < 4; ++kc) {
      size_t off = (size_t)(g * 128 + col) * 128 + kc * 32 + lk * 8;
      wHi[g][kc] = *(const short8v*)(wHiG + off);
      wLo[g][kc] = *(const short8v*)(wLoG + off);
    }
#pragma unroll
  for (int kc = 0; kc < 4; ++kc)
    w1f[kc] = *(const short8v*)(w1t + (size_t)col * 128 + kc * 32 + lk * 8);

  const float bhh_r = bhh[col], bhh_z = bhh[col + 128], bhh_n = bhh[col + 256];
  const float b1v = beta_b1[col];
  float w2v[4];
#pragma unroll
  for (int e = 0; e < 4; ++e) w2v[e] = beta_W2[col * 4 + e];
  float hprev[2][4] = {{0.f, 0.f, 0.f, 0.f}, {0.f, 0.f, 0.f, 0.f}};
  const f32x4 vzero = {0.f, 0.f, 0.f, 0.f};
  __syncthreads();

  for (int t = 0; t < kNL; ++t) {
    const int l_gi = dir ? ((i_idx + 31 - t) & 31) : ((i_idx + t) & 31);
    const int l_out = dir ? (31 - t) : t;
    f32x4 accS[2][3];
#pragma unroll
    for (int rt = 0; rt < 2; ++rt)
#pragma unroll
      for (int g = 0; g < 3; ++g) accS[rt][g] = vzero;
#pragma unroll
    for (int kc = 0; kc < 4; ++kc) {
      const int ko = kc * 32 + lk * 8;
      short8v a0 = *(const short8v*)&hHi[lc][ko];
      short8v a1 = *(const short8v*)&hHi[16 + lc][ko];
      short8v c0 = *(const short8v*)&hLo[lc][ko];
      short8v c1 = *(const short8v*)&hLo[16 + lc][ko];
#pragma unroll
      for (int g = 0; g < 3; ++g) {
        accS[0][g] = __builtin_amdgcn_mfma_f32_16x16x32_bf16(a0, wHi[g][kc], accS[0][g], 0, 0, 0);
        accS[1][g] = __builtin_amdgcn_mfma_f32_16x16x32_bf16(a1, wHi[g][kc], accS[1][g], 0, 0, 0);
        accS[0][g] = __builtin_amdgcn_mfma_f32_16x16x32_bf16(c0, wHi[g][kc], accS[0][g], 0, 0, 0);
        accS[1][g] = __builtin_amdgcn_mfma_f32_16x16x32_bf16(c1, wHi[g][kc], accS[1][g], 0, 0, 0);
        accS[0][g] = __builtin_amdgcn_mfma_f32_16x16x32_bf16(a0, wLo[g][kc], accS[0][g], 0, 0, 0);
        accS[1][g] = __builtin_amdgcn_mfma_f32_16x16x32_bf16(a1, wLo[g][kc], accS[1][g], 0, 0, 0);
      }
    }
#pragma unroll
    for (int rt = 0; rt < 2; ++rt) {
#pragma unroll
      for (int reg = 0; reg < 4; ++reg) {
        const int row = rt * 16 + lk * 4 + reg;
        const size_t gbase = ((size_t)((n0 + row) * kNL + l_gi)) * kG3 + col;
        float gr = Gi[gbase], gz = Gi[gbase + 128], gn = Gi[gbase + 256];
        float sr = accS[rt][0][reg] + bhh_r + gr;
        float sz = accS[rt][1][reg] + bhh_z + gz;
        float sn = accS[rt][2][reg] + bhh_n;
        float rg = 1.f / (1.f + expf(-sr));
        float zg = 1.f / (1.f + expf(-sz));
        float ng = tanhf(gn + rg * sn);
        hprev[rt][reg] = (1.f - zg) * ng + zg * hprev[rt][reg];
      }
    }
    __syncthreads();
#pragma unroll
    for (int rt = 0; rt < 2; ++rt)
#pragma unroll
      for (int reg = 0; reg < 4; ++reg) {
        const int row = rt * 16 + lk * 4 + reg;
        u16 hi = f2bf(hprev[rt][reg]);
        hHi[row][col] = hi;
        hLo[row][col] = f2bf(hprev[rt][reg] - bf2f(hi));
      }
    __syncthreads();
    f32x4 accB[2] = {vzero, vzero};
#pragma unroll
    for (int kc = 0; kc < 4; ++kc) {
      const int ko = kc * 32 + lk * 8;
      short8v a0 = *(const short8v*)&hHi[lc][ko];
      short8v a1 = *(const short8v*)&hHi[16 + lc][ko];
      accB[0] = __builtin_amdgcn_mfma_f32_16x16x32_bf16(a0, w1f[kc], accB[0], 0, 0, 0);
      accB[1] = __builtin_amdgcn_mfma_f32_16x16x32_bf16(a1, w1f[kc], accB[1], 0, 0, 0);
    }
    float p[2][4][4];
#pragma unroll
    for (int rt = 0; rt < 2; ++rt)
#pragma unroll
      for (int reg = 0; reg < 4; ++reg) {
        float h1 = fmaxf(accB[rt][reg] + b1v, 0.f);
#pragma unroll
        for (int e = 0; e < 4; ++e) p[rt][reg][e] = h1 * w2v[e];
      }
#pragma unroll
    for (int m = 1; m < 16; m <<= 1)
#pragma unroll
      for (int rt = 0; rt < 2; ++rt)
#pragma unroll
        for (int reg = 0; reg < 4; ++reg)
#pragma unroll
          for (int e = 0; e < 4; ++e) p[rt][reg][e] += __shfl_xor(p[rt][reg][e], m, 64);
    if (lc == 0) {
#pragma unroll
      for (int rt = 0; rt < 2; ++rt)
#pragma unroll
        for (int reg = 0; reg < 4; ++reg)
#pragma unroll
          for (int e = 0; e < 4; ++e) part[rt * 16 + lk * 4 + reg][w][e] = p[rt][reg][e];
    }
    __syncthreads();
    if (tid < 128) {
      const int row = tid >> 2, e = tid & 3;
      float s = beta_b2[e];
#pragma unroll
      for (int w8 = 0; w8 < 8; ++w8) s += part[row][w8][e];
      float v = 1.f / (1.f + expf(-s));
      Braw[((((size_t)i_idx * kN + (n0 + row)) * kNL + l_out) * 2 + dir) * kNE + e] = v;
    }
  }
}

// ---------------- masks + cumprod + reorder -> P ----------------
__global__ __launch_bounds__(256) void pcompute_kernel(const float* __restrict__ Braw,
                                                       float* __restrict__ P) {
  int tid = blockIdx.x * 256 + threadIdx.x;
  int e = tid & 3;
  int in_ = tid >> 2;
  const float* src = Braw + (size_t)in_ * kNL * 2 * kNE;
  float* dst = P + (size_t)in_ * 2 * kNL * kNE;
  float c = 1.f, zl_prev = 0.f;
  for (int k = 0; k < 2 * kNL; ++k) {
    int l = k >> 1, s = k & 1;
    int lb = s ? (31 - l) : l;
    float braw = src[(lb * 2 + s) * kNE + e];
    float Bk   = (k == 0) ? 0.f : braw;
    float zl   = (k == 63) ? 0.f : Bk;
    float Bfin = (k == 63) ? 1.f : Bk;
    c *= (1.f - zl_prev);
    zl_prev = zl;
    int j = s ? (31 - l) : (32 + l);
    dst[j * kNE + e] = Bfin * c;
  }
}

// ---------------- Phase B v4: weight-stationary-in-budget MFMA ----------------
// 16 blocks x 512 threads (8 waves). launch_bounds(512,1): grid=16 on 256 CUs, so
// 1 block/CU is all we need -> VGPR cap 512, no spills (persistent wG=192 + transients).
// Wave w owns gate/z cols [32w,32w+32) as two 16-col sub-tiles (s=0,1). cWhh bf16-hi
// B-frags persistent in VGPRs; zeta2/heads/cwu/biases streamed from L2 (t-invariant).
// h kept hi+lo; gh = (h_hi + h_lo)*W_hi (drops h*W_lo, ~2^-9 rel). h/z in frag-linear
// LDS [kt][lane][8]: writer C/D scatter == reader contiguous 16B A-frag.
__global__ __launch_bounds__(512, 1) void phaseB4_kernel(
    const float* __restrict__ Mih, const float* __restrict__ Zobs,
    const float* __restrict__ cbhh,
    const u16* __restrict__ fWhhHi, const u16* __restrict__ fZeta,
    const u16* __restrict__ fHead, const u16* __restrict__ fCwu,
    const float* __restrict__ actor_b, const float* __restrict__ ups_b,
    const float* __restrict__ crit_b,
    const float* __restrict__ P, const int* __restrict__ pidx,
    float* __restrict__ out) {
  __shared__ u16 hHi[2][8][64][8];     // 16 KB  frag-linear, double-buffered
  __shared__ u16 hLo[2][8][64][8];     // 16 KB
  __shared__ u16 zHi[8][64][8];        // 8 KB
  __shared__ u16 uHi[16][40];          // u bf16, K padded to 32 (zeros beyond 3)
  __shared__ float uF[16][4];
  __shared__ float aLog[16][33];
  __shared__ float vS[16];
  __shared__ int pS[2][16];
  const int tid = threadIdx.x;
  const int w = tid >> 6, l = tid & 63;
  const int lc = l & 15, lg = l >> 4;
  const int n0 = blockIdx.x * 16;
  const f32x4 vzero = {0.f, 0.f, 0.f, 0.f};

  for (int x = tid; x < 2 * 8 * 64 * 8; x += 512) { (&hHi[0][0][0][0])[x] = 0; (&hLo[0][0][0][0])[x] = 0; }
  for (int x = tid; x < 16 * 40; x += 512) (&uHi[0][0])[x] = 0;
  if (tid < 16) pS[0][tid] = pidx[n0 + tid];

  // persistent: cWhh hi B-frags for this wave's 6 sub-tiles (3 gates x s=0,1)
  short8v wG[3][2][8];
#pragma unroll
  for (int g = 0; g < 3; ++g)
#pragma unroll
    for (int s = 0; s < 2; ++s)
#pragma unroll
      for (int kt = 0; kt < 8; ++kt) {
        int f = (g * 16 + 2 * w + s) * 8 + kt;
        wG[g][s][kt] = *(const short8v*)(fWhhHi + ((size_t)f * 64 + l) * 8);
      }
  float bHd = 0.f;
  if (w < 3) {
    int hc = w * 16 + lc;
    bHd = (hc < 32) ? actor_b[hc] : (hc < 36) ? ups_b[hc - 32] : (hc == 36) ? crit_b[0] : 0.f;
  }
  float hreg[2][4] = {{0.f, 0.f, 0.f, 0.f}, {0.f, 0.f, 0.f, 0.f}};
  __syncthreads();

  for (int t = 0; t < kT; ++t) {
    const int cur = t & 1, nxt = cur ^ 1;
    // ===== phase 1: gates + h update, per sub-tile s =====
    short8v uf = *(const short8v*)&uHi[lc][lg * 8];
#pragma unroll
    for (int s = 0; s < 2; ++s) {
      const int tt = 2 * w + s;
      const int col = tt * 16 + lc;
      short8v wUr = *(const short8v*)(fCwu + ((size_t)(0 * 16 + tt) * 64 + l) * 8);
      short8v wUz = *(const short8v*)(fCwu + ((size_t)(1 * 16 + tt) * 64 + l) * 8);
      short8v wUn = *(const short8v*)(fCwu + ((size_t)(2 * 16 + tt) * 64 + l) * 8);
      const float bR = cbhh[col], bZ = cbhh[256 + col], bN = cbhh[512 + col];
      float giR[4], giZ[4], giN[4];
#pragma unroll
      for (int reg = 0; reg < 4; ++reg) {
        int env = 4 * lg + reg;
        const float* mrow = Mih + ((size_t)(n0 + env) * kNL + pS[cur][env]) * kCG3;
        giR[reg] = mrow[col];
        giZ[reg] = mrow[256 + col];
        giN[reg] = mrow[512 + col];
      }
      f32x4 aR = vzero, aZ = vzero, aN = vzero, aU = vzero;
      aR = __builtin_amdgcn_mfma_f32_16x16x32_bf16(uf, wUr, aR, 0, 0, 0);
      aZ = __builtin_amdgcn_mfma_f32_16x16x32_bf16(uf, wUz, aZ, 0, 0, 0);
      aU = __builtin_amdgcn_mfma_f32_16x16x32_bf16(uf, wUn, aU, 0, 0, 0);
#pragma unroll
      for (int kt = 0; kt < 8; ++kt) {
        short8v ah = *(const short8v*)&hHi[cur][kt][l][0];
        short8v al = *(const short8v*)&hLo[cur][kt][l][0];
        aR = __builtin_amdgcn_mfma_f32_16x16x32_bf16(ah, wG[0][s][kt], aR, 0, 0, 0);
        aR = __builtin_amdgcn_mfma_f32_16x16x32_bf16(al, wG[0][s][kt], aR, 0, 0, 0);
        aZ = __builtin_amdgcn_mfma_f32_16x16x32_bf16(ah, wG[1][s][kt], aZ, 0, 0, 0);
        aZ = __builtin_amdgcn_mfma_f32_16x16x32_bf16(al, wG[1][s][kt], aZ, 0, 0, 0);
        aN = __builtin_amdgcn_mfma_f32_16x16x32_bf16(ah, wG[2][s][kt], aN, 0, 0, 0);
        aN = __builtin_amdgcn_mfma_f32_16x16x32_bf16(al, wG[2][s][kt], aN, 0, 0, 0);
      }
      const int L0 = (s * 2 + (lc >> 3)) * 16;   // + env
      const int j = lc & 7;
#pragma unroll
      for (int reg = 0; reg < 4; ++reg) {
        float sr  = aR[reg] + bR + giR[reg];
        float sz  = aZ[reg] + bZ + giZ[reg];
        float ghn = aN[reg] + bN;
        float gin = aU[reg] + giN[reg];
        float rg = 1.f / (1.f + expf(-sr));
        float zg = 1.f / (1.f + expf(-sz));
        float ng = tanhf(gin + rg * ghn);
        hreg[s][reg] = (1.f - zg) * ng + zg * hreg[s][reg];
        int env = 4 * lg + reg;
        u16 hh = f2bf(hreg[s][reg]);
        hHi[nxt][w][L0 + env][j] = hh;
        hLo[nxt][w][L0 + env][j] = f2bf(hreg[s][reg] - bf2f(hh));
      }
    }
    __syncthreads();   // B1: h_t visible
    // ===== phase 2: z = relu(Zobs + h @ zeta2h), per sub-tile s =====
#pragma unroll
    for (int s = 0; s < 2; ++s) {
      const int tt = 2 * w + s;
      const int col = tt * 16 + lc;
      float zo[4];
#pragma unroll
      for (int reg = 0; reg < 4; ++reg)
        zo[reg] = Zobs[((size_t)t * kN + n0 + 4 * lg + reg) * kHID + col];
      f32x4 az = vzero;
#pragma unroll
      for (int kt = 0; kt < 8; ++kt) {
        short8v zb = *(const short8v*)(fZeta + ((size_t)(tt * 8 + kt) * 64 + l) * 8);
        short8v ah = *(const short8v*)&hHi[nxt][kt][l][0];
        short8v al = *(const short8v*)&hLo[nxt][kt][l][0];
        az = __builtin_amdgcn_mfma_f32_16x16x32_bf16(ah, zb, az, 0, 0, 0);
        az = __builtin_amdgcn_mfma_f32_16x16x32_bf16(al, zb, az, 0, 0, 0);
      }
      const int L0 = (s * 2 + (lc >> 3)) * 16;
      const int j = lc & 7;
#pragma unroll
      for (int reg = 0; reg < 4; ++reg) {
        float zv = fmaxf(az[reg] + zo[reg], 0.f);
        zHi[w][L0 + 4 * lg + reg][j] = f2bf(zv);
      }
    }
    __syncthreads();   // B2: z visible
    // ===== phase 3: heads (waves 0..2) + pidx prefetch (wave 7) =====
    if (w < 3) {
      f32x4 ahd = vzero;
#pragma unroll
      for (int kt = 0; kt < 8; ++kt) {
        short8v hb = *(const short8v*)(fHead + ((size_t)(w * 8 + kt) * 64 + l) * 8);
        short8v zf = *(const short8v*)&zHi[kt][l][0];
        ahd = __builtin_amdgcn_mfma_f32_16x16x32_bf16(zf, hb, ahd, 0, 0, 0);
      }
      if (w < 2) {
#pragma unroll
        for (int reg = 0; reg < 4; ++reg)
          aLog[4 * lg + reg][w * 16 + lc] = ahd[reg] + bHd;
      } else {
        if (lc < 4) {
#pragma unroll
          for (int reg = 0; reg < 4; ++reg) {
            float lq = ahd[reg] + bHd;
            float mx = lq;
            mx = fmaxf(mx, __shfl_xor(mx, 1, 64));
            mx = fmaxf(mx, __shfl_xor(mx, 2, 64));
            float ex = expf(lq - mx);
            float su = ex;
            su += __shfl_xor(su, 1, 64);
            su += __shfl_xor(su, 2, 64);
            float uv = ex / su;
            int env = 4 * lg + reg;
            uF[env][lc] = uv;
            uHi[env][lc] = f2bf(uv);
          }
        } else if (lc == 4) {
#pragma unroll
          for (int reg = 0; reg < 4; ++reg) vS[4 * lg + reg] = ahd[reg] + bHd;
        }
      }
    } else if (w == 7 && l < 16) {
      if (t + 1 < kT) pS[nxt][l] = pidx[(t + 1) * kN + n0 + l];
    }
    __syncthreads();   // B3: logits/u/v/pS visible
    // ===== phase 4: actor softmax + outputs (all 512 threads: 16 envs x 32) =====
    {
      int env = tid >> 5, i = tid & 31;
      int n = n0 + env;
      float* orow = out + ((size_t)t * kN + n) * 97;
      float a = aLog[env][i];
      float m = a;
#pragma unroll
      for (int mm = 1; mm < 32; mm <<= 1) m = fmaxf(m, __shfl_xor(m, mm, 64));
      float ex = expf(a - m), ssum = ex;
#pragma unroll
      for (int mm = 1; mm < 32; mm <<= 1) ssum += __shfl_xor(ssum, mm, 64);
      orow[i] = ex / ssum;
      const float* prow = P + ((size_t)pS[cur][env] * kN + n) * (2 * kNL) * kNE;
      float u0 = uF[env][0], u1 = uF[env][1], u2 = uF[env][2], u3 = uF[env][3];
      float4 wv = *(const float4*)&prow[i * 4];
      orow[32 + i] = wv.x * u0 + wv.y * u1 + wv.z * u2 + wv.w * u3;
      float4 wv2 = *(const float4*)&prow[(32 + i) * 4];
      orow[64 + i] = wv2.x * u0 + wv2.y * u1 + wv2.z * u2 + wv2.w * u3;
      if (i == 0) orow[96] = vS[env];
    }
    __syncthreads();   // B4: uHi/pS safe for next step
  }
}

// ---------------- launch ----------------
extern "C" void kernel_launch(void* const* d_in, const int* in_sizes, int n_in,
                              void* d_out, int out_size, void* d_ws, size_t ws_size,
                              hipStream_t stream) {
  (void)in_sizes; (void)n_in; (void)out_size; (void)ws_size;
  const int*   lines   = (const int*)d_in[0];
  const float* obs     = (const float*)d_in[1];
  const int*   D       = (const int*)d_in[2];
  const float* embed_W = (const float*)d_in[3];
  const float* gWih_f  = (const float*)d_in[4];
  const float* gWhh_f  = (const float*)d_in[5];
  const float* gbih_f  = (const float*)d_in[6];
  const float* gbhh_f  = (const float*)d_in[7];
  const float* gWih_b  = (const float*)d_in[8];
  const float* gWhh_b  = (const float*)d_in[9];
  const float* gbih_b  = (const float*)d_in[10];
  const float* gbhh_b  = (const float*)d_in[11];
  const float* beta_W1 = (const float*)d_in[12];
  const float* beta_b1 = (const float*)d_in[13];
  const float* beta_W2 = (const float*)d_in[14];
  const float* beta_b2 = (const float*)d_in[15];
  const float* cWih    = (const float*)d_in[16];
  const float* cWhh    = (const float*)d_in[17];
  const float* cbih    = (const float*)d_in[18];
  const float* cbhh    = (const float*)d_in[19];
  const float* zeta2_W = (const float*)d_in[20];
  const float* zeta2_b = (const float*)d_in[21];
  const float* actor_W = (const float*)d_in[22];
  const float* actor_b = (const float*)d_in[23];
  const float* ups_W   = (const float*)d_in[24];
  const float* ups_b   = (const float*)d_in[25];
  const float* crit_W  = (const float*)d_in[26];
  const float* crit_b  = (const float*)d_in[27];

  float* ws   = (float*)d_ws;
  float* M    = ws + oM;
  float* Gif  = ws + oGif;
  float* Gib  = ws + oGib;
  float* Mih  = ws + oMih;
  float* Zobs = ws + oZobs;
  float* Braw = ws + oBraw;
  float* Pbuf = ws + oP;
  int*   pidx = (int*)(ws + oPidx);
  u16*   whhHiF = (u16*)(ws + oWhTf);
  u16*   whhLoF = whhHiF + (size_t)kG3 * kTES;
  u16*   whhHiB = (u16*)(ws + oWhTb);
  u16*   whhLoB = whhHiB + (size_t)kG3 * kTES;
  u16*   w1t    = (u16*)(ws + oW1T);
  u16* fWhhHi = (u16*)(ws + oFrag);
  u16* fZeta  = fWhhHi + 196608;
  u16* fHead  = fZeta + 65536;
  u16* fCwu   = fHead + 12288;
  float* outF = (float*)d_out;

  embed_kernel<<<kRows * kTES / 256, 256, 0, stream>>>(lines, embed_W, M);
  bfsplit_kernel<<<(kG3 * kTES + 255) / 256, 256, 0, stream>>>(gWhh_f, whhHiF, whhLoF, kG3 * kTES);
  bfsplit_kernel<<<(kG3 * kTES + 255) / 256, 256, 0, stream>>>(gWhh_b, whhHiB, whhLoB, kG3 * kTES);
  w1t_kernel<<<(kTES * kTES + 255) / 256, 256, 0, stream>>>(beta_W1, w1t);
  packWhh_kernel<<<196608 / 256, 256, 0, stream>>>(cWhh, fWhhHi);
  packZeta_kernel<<<65536 / 256, 256, 0, stream>>>(zeta2_W, fZeta);
  packHead_kernel<<<12288 / 256, 256, 0, stream>>>(actor_W, ups_W, crit_W, fHead);
  packCwu_kernel<<<24576 / 256, 256, 0, stream>>>(cWih, fCwu);
  pidx_kernel<<<1, kN, 0, stream>>>(D, pidx);

  {
    dim3 g(kG3 / 64, kRows / 64);
    gemm_bias_kernel<<<g, 256, 0, stream>>>(M, gWih_f, gbih_f, Gif, kRows, kG3, kTES, kTES, kTES, kG3, 1);
    gemm_bias_kernel<<<g, 256, 0, stream>>>(M, gWih_b, gbih_b, Gib, kRows, kG3, kTES, kTES, kTES, kG3, 1);
  }
  {
    dim3 g(kCG3 / 64, kRows / 64);
    gemm_bias_kernel<<<g, 256, 0, stream>>>(M, cWih, cbih, Mih, kRows, kCG3, kTES, kTES, kTES + kNE, kCG3, 1);
  }
  {
    dim3 g(kHID / 64, (kT * kN) / 64);
    gemm_bias_kernel<<<g, 256, 0, stream>>>(obs, zeta2_W, zeta2_b, Zobs, kT * kN, kHID, kOBSD, kOBSD, kHID, kHID, 0);
  }

  gru_beta_mfma_kernel<<<512, 512, 0, stream>>>(Gif, Gib, whhHiF, whhLoF, whhHiB, whhLoB,
                                                gbhh_f, gbhh_b, w1t, beta_b1, beta_W2, beta_b2, Braw);
  pcompute_kernel<<<(kNL * kN * kNE) / 256, 256, 0, stream>>>(Braw, Pbuf);
  phaseB4_kernel<<<16, 512, 0, stream>>>(Mih, Zobs, cbhh, fWhhHi, fZeta, fHead, fCwu,
                                         actor_b, ups_b, crit_b, Pbuf, pidx, outF);
}